// Round 2
// baseline (750.943 us; speedup 1.0000x reference)
//
#include <hip/hip_runtime.h>

#define HW 4096

// ------- kernel A+W merged: instance-norm stats (b<9216) + weight transposes -------
__global__ __launch_bounds__(256) void k_stats_wx(
    const float* __restrict__ corr, float* __restrict__ scl,
    float* __restrict__ shf,
    const float* __restrict__ p0, const float* __restrict__ p1,
    const float* __restrict__ p2, const float* __restrict__ p3,
    const float* __restrict__ p4, const float* __restrict__ p5,
    float* __restrict__ wT, const float* __restrict__ w1s,
    const float* __restrict__ w2s, const float* __restrict__ w1c,
    const float* __restrict__ w2c, float* __restrict__ wm) {
  int t = threadIdx.x;
  if (blockIdx.x < 9216) {
    int g = blockIdx.x;  // linear over [q][r][ns][c]
    const float4* p = (const float4*)(corr + (size_t)g * HW);
    float s = 0.f, s2 = 0.f;
#pragma unroll
    for (int i = 0; i < 4; i++) {
      float4 v = p[t + i * 256];
      s += v.x + v.y + v.z + v.w;
      s2 += v.x * v.x + v.y * v.y + v.z * v.z + v.w * v.w;
    }
#pragma unroll
    for (int o = 32; o > 0; o >>= 1) {
      s += __shfl_down(s, o, 64);
      s2 += __shfl_down(s2, o, 64);
    }
    __shared__ float ls[4], ls2[4];
    int wid = t >> 6;
    if ((t & 63) == 0) { ls[wid] = s; ls2[wid] = s2; }
    __syncthreads();
    if (t == 0) {
      float S = ls[0] + ls[1] + ls[2] + ls[3];
      float S2 = ls2[0] + ls2[1] + ls2[2] + ls2[3];
      float m = S * (1.f / HW);
      float var = S2 * (1.f / HW) - m * m;
      float r = rsqrtf(var + 1e-5f);
      scl[g] = r;
      shf[g] = -m * r;
    }
    return;
  }
  int b = blockIdx.x - 9216;  // 96 conv chunks + 53 mlp chunks
  if (b < 96) {
    int arr = b >> 4;
    int chunk = b & 15;
    const float* src = (arr == 0) ? p0
                       : (arr == 1) ? p1
                       : (arr == 2) ? p2
                       : (arr == 3) ? p3
                       : (arr == 4) ? p4 : p5;
    float* dst = wT + arr * 36864;
#pragma unroll
    for (int i = 0; i < 9; i++) {
      int e = chunk * 2304 + i * 256 + t;  // 0..36863
      int oc = e / 576;
      int rem = e - oc * 576;  // ic*9+j
      dst[rem * 64 + oc] = src[e];
    }
  } else {
    int i = (b - 96) * 256 + t;
    if (i < 4608) {
      int c = i >> 6, o = i & 63;
      wm[i] = w1s[o * 72 + c];
    } else if (i < 8704) {
      int j = i - 4608;
      int c = j >> 6, o = j & 63;
      wm[i] = w2s[o * 64 + c];
    } else if (i < 9472) {
      int j = i - 8704;
      int c = j >> 6, o = j & 63;
      wm[i] = w1c[o * 12 + c];
    } else if (i < 13568) {
      int j = i - 9472;
      int c = j >> 6, o = j & 63;
      wm[i] = w2c[o * 64 + c];
    }
  }
}

// ---------------- kernel B: ref_score -> rs[(q*32+r)*4+ns][px] ----------------
__global__ __launch_bounds__(256) void k_refscore(const float* __restrict__ corr,
                                                  const float* __restrict__ scl,
                                                  const float* __restrict__ shf,
                                                  float* __restrict__ rs) {
  int b = blockIdx.x;     // 2048
  int grp = b >> 2;       // 0..511
  int i4 = (b & 3) * 256 + threadIdx.x;  // float4 index 0..1023
  const float* base = corr + (size_t)grp * 18 * HW;
  float4 acc = make_float4(0.f, 0.f, 0.f, 0.f);
  float sh = 0.f;
#pragma unroll
  for (int c = 0; c < 18; c++) {
    float s = scl[grp * 18 + c];
    sh += shf[grp * 18 + c];
    float4 v = ((const float4*)(base + c * HW))[i4];
    acc.x += v.x * s; acc.y += v.y * s; acc.z += v.z * s; acc.w += v.w * s;
  }
  const float inv = 1.f / 18.f;
  float4 o;
  o.x = (acc.x + sh) * inv; o.y = (acc.y + sh) * inv;
  o.z = (acc.z + sh) * inv; o.w = (acc.w + sh) * inv;
  ((float4*)(rs + (size_t)grp * HW))[i4] = o;
}

// ---------------- kernel C: top-4 of 32, LDS-staged ----------------
__global__ __launch_bounds__(256) void k_topk(const float* __restrict__ rs,
                                              int* __restrict__ topidx) {
  __shared__ float st[32 * 256];  // 32 KB
  int b = blockIdx.x;             // 256 = q*4ns*16pxc
  int pxc = b & 15;
  int ns = (b >> 4) & 3;
  int q = b >> 6;
  int t = threadIdx.x;
  int pxb = pxc * 256;
#pragma unroll 8
  for (int r = 0; r < 32; r++)
    st[r * 256 + t] = rs[((q * 32 + r) * 4 + ns) * HW + pxb + t];
  __syncthreads();
  float v[32];
#pragma unroll
  for (int r = 0; r < 32; r++) v[r] = st[r * 256 + t];
  unsigned mask = 0;
  int sel[4];
#pragma unroll
  for (int k = 0; k < 4; k++) {
    float best = -3.4e38f;
    int bi = 0;
#pragma unroll
    for (int r = 0; r < 32; r++) {
      bool take = (!(mask & (1u << r))) && (v[r] > best);
      best = take ? v[r] : best;
      bi = take ? r : bi;
    }
    sel[k] = bi;
    mask |= (1u << bi);
  }
  ((int4*)topidx)[(q * 4 + ns) * HW + pxb + t] =
      make_int4(sel[0], sel[1], sel[2], sel[3]);
}

// ---- fused gather + both MLPs: stream-select 4 knn rows into regs, norm,
// ---- run scale-MLP (72->64->64) and score-MLP (12->64->64), ns-max, store.
#define L1GRP(VV, OFF)                                        \
  _Pragma("unroll") for (int c = 0; c < 18; c++) {            \
    const float* wr = wm + (OFF + c) * 64;                    \
    float x = VV[c];                                          \
    _Pragma("unroll") for (int o = 0; o < 64; o++)            \
        h[o] = fmaf(wr[o], x, h[o]);                          \
  }

#define NSMAX_STORE(OUTP)                                     \
  _Pragma("unroll") for (int og = 0; og < 8; og++) {          \
    _Pragma("unroll") for (int j = 0; j < 8; j++)             \
        red8[j * 256 + t] = a[og * 8 + j];                    \
    __syncthreads();                                          \
    _Pragma("unroll") for (int jj = 0; jj < 2; jj++) {        \
      int j2 = ns * 2 + jj;                                   \
      float m = red8[j2 * 256 + lane];                        \
      _Pragma("unroll") for (int n2 = 1; n2 < 4; n2++)        \
          m = fmaxf(m, red8[j2 * 256 + n2 * 64 + lane]);      \
      OUTP[(size_t)(q * 64 + og * 8 + j2) * HW + px] = m;     \
    }                                                         \
    __syncthreads();                                          \
  }

__global__ __launch_bounds__(256, 1) void k_gmlp(
    const float* __restrict__ corr, const float* __restrict__ scl,
    const float* __restrict__ shf, const int* __restrict__ topidx,
    const float* __restrict__ wm, const float* __restrict__ b1s,
    const float* __restrict__ b2s, const float* __restrict__ b1c,
    const float* __restrict__ b2c, float* __restrict__ xs,
    float* __restrict__ xc) {
  __shared__ float lscl[2304], lshf[2304];
  __shared__ float red8[8 * 256];
  int blk = blockIdx.x;  // 256 = q*64 + pxc
  int q = blk >> 6, pxc = blk & 63;
  int t = threadIdx.x;
  int ns = t >> 6;  // wave-uniform
  int lane = t & 63;
  int px = pxc * 64 + lane;

  for (int i = t; i < 2304; i += 256) {
    lscl[i] = scl[q * 2304 + i];
    lshf[i] = shf[q * 2304 + i];
  }
  int4 ti = ((const int4*)topidx)[(q * 4 + ns) * HW + px];
  __syncthreads();
  int rk0 = ti.x, rk1 = ti.y, rk2 = ti.z, rk3 = ti.w;

  // stream all 32 r, keep the 4 selected (static reg indices only)
  float v0[18], v1[18], v2[18], v3[18];
#pragma unroll
  for (int c = 0; c < 18; c++) { v0[c] = 0.f; v1[c] = 0.f; v2[c] = 0.f; v3[c] = 0.f; }
  const float* cb = corr + ((size_t)((q * 32) * 4 + ns) * 18) * HW + px;
#pragma unroll 2
  for (int r = 0; r < 32; r++) {
    const float* br = cb + (size_t)r * (72 * HW);
    bool m0 = (r == rk0), m1 = (r == rk1), m2 = (r == rk2), m3 = (r == rk3);
#pragma unroll
    for (int c = 0; c < 18; c++) {
      float x = br[c * HW];
      v0[c] = m0 ? x : v0[c];
      v1[c] = m1 ? x : v1[c];
      v2[c] = m2 ? x : v2[c];
      v3[c] = m3 ? x : v3[c];
    }
  }
  // normalize selected rows (per-lane LDS gathers)
  int e0 = rk0 * 72 + ns * 18, e1 = rk1 * 72 + ns * 18;
  int e2 = rk2 * 72 + ns * 18, e3 = rk3 * 72 + ns * 18;
#pragma unroll
  for (int c = 0; c < 18; c++) {
    v0[c] = fmaf(v0[c], lscl[e0 + c], lshf[e0 + c]);
    v1[c] = fmaf(v1[c], lscl[e1 + c], lshf[e1 + c]);
    v2[c] = fmaf(v2[c], lscl[e2 + c], lshf[e2 + c]);
    v3[c] = fmaf(v3[c], lscl[e3 + c], lshf[e3 + c]);
  }
  // level means for score path: xsc[k*3+l]
  float xsc[12];
#pragma unroll
  for (int l = 0; l < 3; l++) {
    float s0 = 0.f, s1 = 0.f, s2 = 0.f, s3 = 0.f;
#pragma unroll
    for (int j = 0; j < 6; j++) {
      s0 += v0[l * 6 + j]; s1 += v1[l * 6 + j];
      s2 += v2[l * 6 + j]; s3 += v3[l * 6 + j];
    }
    xsc[0 + l] = s0 * (1.f / 6.f);
    xsc[3 + l] = s1 * (1.f / 6.f);
    xsc[6 + l] = s2 * (1.f / 6.f);
    xsc[9 + l] = s3 * (1.f / 6.f);
  }

  // ---- scale path: 72 -> 64 relu -> 64
  float h[64];
#pragma unroll
  for (int o = 0; o < 64; o++) h[o] = b1s[o];
  L1GRP(v0, 0)
  L1GRP(v1, 18)
  L1GRP(v2, 36)
  L1GRP(v3, 54)
#pragma unroll
  for (int o = 0; o < 64; o++) h[o] = fmaxf(h[o], 0.f);
  float a[64];
#pragma unroll
  for (int o = 0; o < 64; o++) a[o] = b2s[o];
#pragma unroll
  for (int c = 0; c < 64; c++) {
    const float* wr = wm + 4608 + c * 64;
    float x = h[c];
#pragma unroll
    for (int o = 0; o < 64; o++) a[o] = fmaf(wr[o], x, a[o]);
  }
  NSMAX_STORE(xs)

  // ---- score path: 12 -> 64 relu -> 64
#pragma unroll
  for (int o = 0; o < 64; o++) h[o] = b1c[o];
#pragma unroll
  for (int c = 0; c < 12; c++) {
    const float* wr = wm + 8704 + c * 64;
    float x = xsc[c];
#pragma unroll
    for (int o = 0; o < 64; o++) h[o] = fmaf(wr[o], x, h[o]);
  }
#pragma unroll
  for (int o = 0; o < 64; o++) h[o] = fmaxf(h[o], 0.f);
#pragma unroll
  for (int o = 0; o < 64; o++) a[o] = b2c[o];
#pragma unroll
  for (int c = 0; c < 64; c++) {
    const float* wr = wm + 9472 + c * 64;
    float x = h[c];
#pragma unroll
    for (int o = 0; o < 64; o++) a[o] = fmaf(wr[o], x, a[o]);
  }
  NSMAX_STORE(xc)
}

// ---- merged big 3x3 conv v3: 2 rows x 16 oc per thread (og=4 -> half the
// ---- redundant staging vs og=8).  grid 384 = hi(12: og*3+head)*32 + q*8 + rt.
// LDS 16ic x 10 rows x 72 stride (data at col 4..67, pads col 3 & 68) = 46 KB.
template <bool RELU>
__global__ __launch_bounds__(256) void k_conv3h(
    const float* __restrict__ in0, const float* __restrict__ in1,
    const float* __restrict__ in2, const float* __restrict__ w0,
    const float* __restrict__ w1, const float* __restrict__ w2,
    const float* __restrict__ bb0, const float* __restrict__ bb1,
    const float* __restrict__ bb2, float* __restrict__ o0,
    float* __restrict__ o1, float* __restrict__ o2) {
  __shared__ float tile[16 * 10 * 72];  // 46.1 KB -> 3 blocks/CU
  int b = blockIdx.x;
  int hi = b >> 5;  // og*3 + head, og in 0..3
  int og = hi / 3;
  int head = hi - og * 3;
  int q = (b >> 3) & 3;
  int rt = b & 7;
  const float* in = head == 0 ? in0 : head == 1 ? in1 : in2;
  const float* wT = head == 0 ? w0 : head == 1 ? w1 : w2;
  const float* bb = head == 0 ? bb0 : head == 1 ? bb1 : bb2;
  float* outp = head == 0 ? o0 : head == 1 ? o1 : o2;

  int t = threadIdx.x;
  int w = t & 63;
  int wr = t >> 6;       // 0..3 (wave-uniform): thread rows 2wr, 2wr+1
  int lane4 = t & 15;    // staging: float4 col
  int rgrp = t >> 4;     // staging: 16 rows/pass
  float acc[2][16];
#pragma unroll
  for (int pr = 0; pr < 2; pr++)
#pragma unroll
    for (int o = 0; o < 16; o++) acc[pr][o] = 0.f;
  const float* inq = in + (size_t)q * 64 * HW;

  for (int icc = 0; icc < 4; icc++) {
    __syncthreads();
    // edge pads (rows 0..159): col 3 (img -1) and col 68 (img 64)
    if (t < 160) { tile[t * 72 + 3] = 0.f; tile[t * 72 + 68] = 0.f; }
    // stage 16 ic x 10 rows x 64 cols as float4
#pragma unroll
    for (int p = 0; p < 10; p++) {
      int idx = p * 16 + rgrp;  // 0..159
      int ch = idx / 10;
      int r = idx - ch * 10;
      int grow = rt * 8 + r - 1;
      float4 val = make_float4(0.f, 0.f, 0.f, 0.f);
      if (grow >= 0 && grow < 64)
        val = *(const float4*)(inq + (size_t)(icc * 16 + ch) * HW + grow * 64 +
                               lane4 * 4);
      *(float4*)(tile + idx * 72 + 4 + lane4 * 4) = val;
    }
    __syncthreads();
#pragma unroll 2
    for (int ic = 0; ic < 16; ic++) {
      // x window: 4 tile rows x 3 cols
      float xv[4][3];
      const float* tb = tile + (ic * 10 + wr * 2) * 72 + w + 3;
#pragma unroll
      for (int rr = 0; rr < 4; rr++)
#pragma unroll
        for (int dc = 0; dc < 3; dc++) xv[rr][dc] = tb[rr * 72 + dc];
      const float* wb = wT + (size_t)(icc * 16 + ic) * 9 * 64 + og * 16;
#pragma unroll
      for (int dr = 0; dr < 3; dr++)
#pragma unroll
        for (int dc = 0; dc < 3; dc++) {
          const float* wv = wb + (dr * 3 + dc) * 64;
#pragma unroll
          for (int o = 0; o < 16; o++) {
            float wj = wv[o];
            acc[0][o] = fmaf(wj, xv[0 + dr][dc], acc[0][o]);
            acc[1][o] = fmaf(wj, xv[1 + dr][dc], acc[1][o]);
          }
        }
    }
  }
#pragma unroll
  for (int pr = 0; pr < 2; pr++) {
    int orow = rt * 8 + wr * 2 + pr;
#pragma unroll
    for (int o = 0; o < 16; o++) {
      float rz = acc[pr][o] + bb[og * 16 + o];
      if (RELU) rz = fmaxf(rz, 0.f);
      outp[((size_t)q * 64 + og * 16 + o) * HW + orow * 64 + w] = rz;
    }
  }
}

// ---- merged small 3x3 conv (heads: OC=1,2,1), 1-row blocks ----
__global__ __launch_bounds__(256) void k_convSh(
    const float* __restrict__ in0, const float* __restrict__ in1,
    const float* __restrict__ in2, const float* __restrict__ wt0,
    const float* __restrict__ wt1, const float* __restrict__ wt2,
    const float* __restrict__ bb0, const float* __restrict__ bb1,
    const float* __restrict__ bb2, float* __restrict__ o0,
    float* __restrict__ o1, float* __restrict__ o2) {
  __shared__ float tile[64 * 3 * 66];  // 50.7 KB
  __shared__ float red[4 * 2 * 64];
  int b = blockIdx.x;  // 768 = head*256 + q*64 + row
  int head = b >> 8;
  int q = (b >> 6) & 3;
  int row = b & 63;
  const float* in = head == 0 ? in0 : head == 1 ? in1 : in2;
  const float* wt = head == 0 ? wt0 : head == 1 ? wt1 : wt2;
  const float* bb = head == 0 ? bb0 : head == 1 ? bb1 : bb2;
  float* outp = head == 0 ? o0 : head == 1 ? o1 : o2;
  int noc = (head == 1) ? 2 : 1;

  int t = threadIdx.x;
  int w = t & 63;
  int sub = t >> 6;
  if (t < 192) { tile[t * 66] = 0.f; tile[t * 66 + 65] = 0.f; }
  __syncthreads();
  const float* inq = in + (size_t)q * 64 * HW;
#pragma unroll
  for (int i = 0; i < 48; i++) {
    int idx = i * 4 + sub;
    int ic = idx / 3;
    int r = idx - ic * 3;
    int grow = row + r - 1;
    float val = 0.f;
    if (grow >= 0 && grow < 64) val = inq[(size_t)ic * HW + grow * 64 + w];
    tile[idx * 66 + 1 + w] = val;
  }
  __syncthreads();
  float acc0 = 0.f, acc1 = 0.f;
#pragma unroll 4
  for (int i = 0; i < 16; i++) {
    int ic = sub * 16 + i;
    float x[9];
#pragma unroll
    for (int dr = 0; dr < 3; dr++)
#pragma unroll
      for (int dc = 0; dc < 3; dc++)
        x[dr * 3 + dc] = tile[(ic * 3 + dr) * 66 + w + dc];
    const float* wb = wt + (size_t)ic * 9;
#pragma unroll
    for (int j = 0; j < 9; j++) acc0 += wb[j] * x[j];
    if (noc == 2) {
      const float* wb1 = wt + 576 + (size_t)ic * 9;
#pragma unroll
      for (int j = 0; j < 9; j++) acc1 += wb1[j] * x[j];
    }
  }
  red[(sub * 2 + 0) * 64 + w] = acc0;
  if (noc == 2) red[(sub * 2 + 1) * 64 + w] = acc1;
  __syncthreads();
  if (t < 128) {
    int o = t >> 6;
    if (o < noc) {
      float s = red[(0 * 2 + o) * 64 + w] + red[(1 * 2 + o) * 64 + w] +
                red[(2 * 2 + o) * 64 + w] + red[(3 * 2 + o) * 64 + w] + bb[o];
      outp[((size_t)q * noc + o) * HW + row * 64 + w] = s;
    }
  }
}

// ---------------- final: argmax + pos/scl ----------------
__global__ __launch_bounds__(256) void k_final(const float* __restrict__ scores,
                                               const float* __restrict__ scales,
                                               const float* __restrict__ offsets,
                                               float* __restrict__ pos,
                                               float* __restrict__ sclo) {
  int q = blockIdx.x, t = threadIdx.x;
  float best = -3.4e38f;
  int bi = 1 << 30;
  for (int i = t; i < HW; i += 256) {
    float v = scores[q * HW + i];
    if (v > best) { best = v; bi = i; }
  }
  __shared__ float bv[256];
  __shared__ int bix[256];
  bv[t] = best;
  bix[t] = bi;
  __syncthreads();
  for (int s = 128; s > 0; s >>= 1) {
    if (t < s) {
      if (bv[t + s] > bv[t] || (bv[t + s] == bv[t] && bix[t + s] < bix[t])) {
        bv[t] = bv[t + s];
        bix[t] = bix[t + s];
      }
    }
    __syncthreads();
  }
  if (t == 0) {
    int sid = bix[0];
    int sy = sid >> 6, sx = sid & 63;
    float o0 = offsets[(q * 2 + 0) * HW + sid];
    float o1 = offsets[(q * 2 + 1) * HW + sid];
    pos[q * 2 + 0] = ((float)sx + o0 + 0.5f) * 8.f - 0.5f;
    pos[q * 2 + 1] = ((float)sy + o1 + 0.5f) * 8.f - 0.5f;
    sclo[q] = exp2f(scales[q * HW + sid]);
  }
}

extern "C" void kernel_launch(void* const* d_in, const int* in_sizes, int n_in,
                              void* d_out, int out_size, void* d_ws, size_t ws_size,
                              hipStream_t stream) {
  const float* corr = (const float*)d_in[0];
  const float* w1s = (const float*)d_in[1];
  const float* b1s = (const float*)d_in[2];
  const float* w2s = (const float*)d_in[3];
  const float* b2s = (const float*)d_in[4];
  const float* w1c = (const float*)d_in[5];
  const float* b1c = (const float*)d_in[6];
  const float* w2c = (const float*)d_in[7];
  const float* b2c = (const float*)d_in[8];

  float* out = (float*)d_out;
  float* pos = out;                   // (4,2)
  float* sclo = out + 8;              // (4,)
  float* scores = out + 12;           // (4,1,64,64)
  float* scales = out + 12 + 16384;   // (4,1,64,64)
  float* offsets = out + 12 + 32768;  // (4,2,64,64)

  char* ws = (char*)d_ws;
  float* st_scl = (float*)(ws + 0);       // 36 KB
  float* st_shf = (float*)(ws + 36864);   // 36 KB
  int* topidx = (int*)(ws + 73728);       // 1 MB
  float* rs = (float*)(ws + 1122304);     // 8.39 MB (dead after k_topk)
  float* wT = (float*)(ws + 19996672);    // 884 KB (big-conv transposed w)
  float* wmT = (float*)(ws + 20881408);   // 54 KB (MLP transposed w)
  float* xs = (float*)(ws + 20971520);    // 4.19 MB
  float* xc = (float*)(ws + 25165824);    // 4.19 MB  (total 29.4 MB)
  // t1/t2 reuse dead regions (stream-ordered):
  float* t1s = rs;                           // rs dead after k_topk
  float* t1o = (float*)((char*)rs + 4194304);
  float* t1c = (float*)((char*)rs + 8388608);
  float* t2c = (float*)((char*)rs + 12582912);
  float* t2s = xs;                           // xs dead after conv layer 1
  float* t2o = xc;                           // xc dead after conv layer 1

  k_stats_wx<<<9365, 256, 0, stream>>>(
      corr, st_scl, st_shf, (const float*)d_in[9], (const float*)d_in[11],
      (const float*)d_in[15], (const float*)d_in[17], (const float*)d_in[21],
      (const float*)d_in[23], wT, w1s, w2s, w1c, w2c, wmT);
  k_refscore<<<2048, 256, 0, stream>>>(corr, st_scl, st_shf, rs);
  k_topk<<<256, 256, 0, stream>>>(rs, topidx);
  k_gmlp<<<256, 256, 0, stream>>>(corr, st_scl, st_shf, topidx, wmT, b1s, b2s,
                                  b1c, b2c, xs, xc);
  // conv layer 1 (all heads): xs->t1s, xc->t1o, xc->t1c
  k_conv3h<true><<<384, 256, 0, stream>>>(
      xs, xc, xc, wT, wT + 2 * 36864, wT + 4 * 36864,
      (const float*)d_in[10], (const float*)d_in[16], (const float*)d_in[22],
      t1s, t1o, t1c);
  // conv layer 2 (all heads): t1*->t2*
  k_conv3h<true><<<384, 256, 0, stream>>>(
      t1s, t1o, t1c, wT + 1 * 36864, wT + 3 * 36864, wT + 5 * 36864,
      (const float*)d_in[12], (const float*)d_in[18], (const float*)d_in[24],
      t2s, t2o, t2c);
  // conv layer 3 (all heads): t2* -> scales/offsets/scores
  k_convSh<<<768, 256, 0, stream>>>(
      t2s, t2o, t2c, (const float*)d_in[13], (const float*)d_in[19],
      (const float*)d_in[25], (const float*)d_in[14], (const float*)d_in[20],
      (const float*)d_in[26], scales, offsets, scores);

  k_final<<<4, 256, 0, stream>>>(scores, scales, offsets, pos, sclo);
}

// Round 3
// 652.861 us; speedup vs baseline: 1.1502x; 1.1502x over previous
//
#include <hip/hip_runtime.h>

#define HW 4096

// ------- kernel A+W merged: instance-norm stats (b<9216) + weight transposes -------
__global__ __launch_bounds__(256) void k_stats_wx(
    const float* __restrict__ corr, float* __restrict__ scl,
    float* __restrict__ shf,
    const float* __restrict__ p0, const float* __restrict__ p1,
    const float* __restrict__ p2, const float* __restrict__ p3,
    const float* __restrict__ p4, const float* __restrict__ p5,
    float* __restrict__ wT, const float* __restrict__ w1s,
    const float* __restrict__ w2s, const float* __restrict__ w1c,
    const float* __restrict__ w2c, float* __restrict__ wm) {
  int t = threadIdx.x;
  if (blockIdx.x < 9216) {
    int g = blockIdx.x;  // linear over [q][r][ns][c]
    const float4* p = (const float4*)(corr + (size_t)g * HW);
    float s = 0.f, s2 = 0.f;
#pragma unroll
    for (int i = 0; i < 4; i++) {
      float4 v = p[t + i * 256];
      s += v.x + v.y + v.z + v.w;
      s2 += v.x * v.x + v.y * v.y + v.z * v.z + v.w * v.w;
    }
#pragma unroll
    for (int o = 32; o > 0; o >>= 1) {
      s += __shfl_down(s, o, 64);
      s2 += __shfl_down(s2, o, 64);
    }
    __shared__ float ls[4], ls2[4];
    int wid = t >> 6;
    if ((t & 63) == 0) { ls[wid] = s; ls2[wid] = s2; }
    __syncthreads();
    if (t == 0) {
      float S = ls[0] + ls[1] + ls[2] + ls[3];
      float S2 = ls2[0] + ls2[1] + ls2[2] + ls2[3];
      float m = S * (1.f / HW);
      float var = S2 * (1.f / HW) - m * m;
      float r = rsqrtf(var + 1e-5f);
      scl[g] = r;
      shf[g] = -m * r;
    }
    return;
  }
  int b = blockIdx.x - 9216;  // 96 conv chunks + 53 mlp chunks
  if (b < 96) {
    int arr = b >> 4;
    int chunk = b & 15;
    const float* src = (arr == 0) ? p0
                       : (arr == 1) ? p1
                       : (arr == 2) ? p2
                       : (arr == 3) ? p3
                       : (arr == 4) ? p4 : p5;
    float* dst = wT + arr * 36864;
#pragma unroll
    for (int i = 0; i < 9; i++) {
      int e = chunk * 2304 + i * 256 + t;  // 0..36863
      int oc = e / 576;
      int rem = e - oc * 576;  // ic*9+j
      dst[rem * 64 + oc] = src[e];
    }
  } else {
    int i = (b - 96) * 256 + t;
    if (i < 4608) {
      int c = i >> 6, o = i & 63;
      wm[i] = w1s[o * 72 + c];
    } else if (i < 8704) {
      int j = i - 4608;
      int c = j >> 6, o = j & 63;
      wm[i] = w2s[o * 64 + c];
    } else if (i < 9472) {
      int j = i - 8704;
      int c = j >> 6, o = j & 63;
      wm[i] = w1c[o * 12 + c];
    } else if (i < 13568) {
      int j = i - 9472;
      int c = j >> 6, o = j & 63;
      wm[i] = w2c[o * 64 + c];
    }
  }
}

// ---------------- kernel B: ref_score -> rs[(q*32+r)*4+ns][px] ----------------
__global__ __launch_bounds__(256) void k_refscore(const float* __restrict__ corr,
                                                  const float* __restrict__ scl,
                                                  const float* __restrict__ shf,
                                                  float* __restrict__ rs) {
  int b = blockIdx.x;     // 2048
  int grp = b >> 2;       // 0..511
  int i4 = (b & 3) * 256 + threadIdx.x;  // float4 index 0..1023
  const float* base = corr + (size_t)grp * 18 * HW;
  float4 acc = make_float4(0.f, 0.f, 0.f, 0.f);
  float sh = 0.f;
#pragma unroll
  for (int c = 0; c < 18; c++) {
    float s = scl[grp * 18 + c];
    sh += shf[grp * 18 + c];
    float4 v = ((const float4*)(base + c * HW))[i4];
    acc.x += v.x * s; acc.y += v.y * s; acc.z += v.z * s; acc.w += v.w * s;
  }
  const float inv = 1.f / 18.f;
  float4 o;
  o.x = (acc.x + sh) * inv; o.y = (acc.y + sh) * inv;
  o.z = (acc.z + sh) * inv; o.w = (acc.w + sh) * inv;
  ((float4*)(rs + (size_t)grp * HW))[i4] = o;
}

// ---------------- kernel C: top-4 of 32, LDS-staged ----------------
__global__ __launch_bounds__(256) void k_topk(const float* __restrict__ rs,
                                              int* __restrict__ topidx) {
  __shared__ float st[32 * 256];  // 32 KB
  int b = blockIdx.x;             // 256 = q*4ns*16pxc
  int pxc = b & 15;
  int ns = (b >> 4) & 3;
  int q = b >> 6;
  int t = threadIdx.x;
  int pxb = pxc * 256;
#pragma unroll 8
  for (int r = 0; r < 32; r++)
    st[r * 256 + t] = rs[((q * 32 + r) * 4 + ns) * HW + pxb + t];
  __syncthreads();
  float v[32];
#pragma unroll
  for (int r = 0; r < 32; r++) v[r] = st[r * 256 + t];
  unsigned mask = 0;
  int sel[4];
#pragma unroll
  for (int k = 0; k < 4; k++) {
    float best = -3.4e38f;
    int bi = 0;
#pragma unroll
    for (int r = 0; r < 32; r++) {
      bool take = (!(mask & (1u << r))) && (v[r] > best);
      best = take ? v[r] : best;
      bi = take ? r : bi;
    }
    sel[k] = bi;
    mask |= (1u << bi);
  }
  ((int4*)topidx)[(q * 4 + ns) * HW + pxb + t] =
      make_int4(sel[0], sel[1], sel[2], sel[3]);
}

// -------- kernel D1: high-occupancy streaming gather+norm -> vbuf ----------
__global__ __launch_bounds__(256) void k_gather(const float* __restrict__ corr,
                                                const float* __restrict__ scl,
                                                const float* __restrict__ shf,
                                                const int* __restrict__ topidx,
                                                float* __restrict__ vbuf) {
  __shared__ float ls[32], lsh[32];
  int b = blockIdx.x;  // 4608 = q x pxc x ns x c
  int c = b % 18;
  int rest = b / 18;
  int ns = rest & 3;
  int pxc = (rest >> 2) & 15;
  int q = rest >> 6;
  int t = threadIdx.x;
  int px = pxc * 256 + t;

  if (t < 32) {
    int g = q * 2304 + t * 72 + ns * 18 + c;
    ls[t] = scl[g];
    lsh[t] = shf[g];
  }
  int4 ti = ((const int4*)topidx)[(q * 4 + ns) * HW + px];
  int rk0 = ti.x, rk1 = ti.y, rk2 = ti.z, rk3 = ti.w;
  __syncthreads();

  const float* base = corr + (size_t)(((q * 32) * 4 + ns) * 18 + c) * HW + px;
  float v0 = 0.f, v1 = 0.f, v2 = 0.f, v3 = 0.f;
#pragma unroll
  for (int r = 0; r < 32; r++) {
    float x = base[(size_t)r * 72 * HW];
    v0 = (rk0 == r) ? x : v0;
    v1 = (rk1 == r) ? x : v1;
    v2 = (rk2 == r) ? x : v2;
    v3 = (rk3 == r) ? x : v3;
  }
  v0 = v0 * ls[rk0] + lsh[rk0];
  v1 = v1 * ls[rk1] + lsh[rk1];
  v2 = v2 * ls[rk2] + lsh[rk2];
  v3 = v3 * ls[rk3] + lsh[rk3];
  size_t ob = (size_t)((q * 4 + ns) * 72 + c) * HW + px;
  vbuf[ob] = v0;
  vbuf[ob + 18 * HW] = v1;
  vbuf[ob + 36 * HW] = v2;
  vbuf[ob + 54 * HW] = v3;
}

// ---- kernel D2: BOTH MLPs fused, single vbuf read, all static reg indexing ----
#define NSMAX_STORE(OUTP)                                     \
  _Pragma("unroll") for (int og = 0; og < 8; og++) {          \
    _Pragma("unroll") for (int j = 0; j < 8; j++)             \
        red8[j * 256 + t] = a[og * 8 + j];                    \
    __syncthreads();                                          \
    _Pragma("unroll") for (int jj = 0; jj < 2; jj++) {        \
      int j2 = ns * 2 + jj;                                   \
      float m = red8[j2 * 256 + lane];                        \
      _Pragma("unroll") for (int n2 = 1; n2 < 4; n2++)        \
          m = fmaxf(m, red8[j2 * 256 + n2 * 64 + lane]);      \
      OUTP[(size_t)(q * 64 + og * 8 + j2) * HW + px] = m;     \
    }                                                         \
    __syncthreads();                                          \
  }

__global__ __launch_bounds__(256, 2) void k_mlpf(
    const float* __restrict__ vbuf, const float* __restrict__ wm,
    const float* __restrict__ b1s, const float* __restrict__ b2s,
    const float* __restrict__ b1c, const float* __restrict__ b2c,
    float* __restrict__ xs, float* __restrict__ xc) {
  __shared__ float red8[8 * 256];
  int blk = blockIdx.x;  // 256 = q*64 + pxc
  int q = blk >> 6, pxc = blk & 63;
  int t = threadIdx.x;
  int ns = t >> 6;  // wave-uniform
  int lane = t & 63;
  int px = pxc * 64 + lane;

  const float* vb = vbuf + (size_t)((q * 4 + ns) * 72) * HW + px;

  float h[64];
#pragma unroll
  for (int o = 0; o < 64; o++) h[o] = b1s[o];
  float xsc[12];
#pragma unroll
  for (int l = 0; l < 12; l++) xsc[l] = 0.f;
  // layer 1 (scale path) + accumulate level means for score path.
  // channel c0+j has flat index k*18 + c' -> level-mean slot (c0+j)/6 (static).
#pragma unroll
  for (int c0 = 0; c0 < 72; c0 += 8) {
    float x[8];
#pragma unroll
    for (int j = 0; j < 8; j++) x[j] = vb[(size_t)(c0 + j) * HW];
#pragma unroll
    for (int j = 0; j < 8; j++) {
      const float* wr = wm + (c0 + j) * 64;  // wave-uniform -> s_load
#pragma unroll
      for (int o = 0; o < 64; o++) h[o] = fmaf(wr[o], x[j], h[o]);
    }
#pragma unroll
    for (int j = 0; j < 8; j++) xsc[(c0 + j) / 6] += x[j];
  }
#pragma unroll
  for (int o = 0; o < 64; o++) h[o] = fmaxf(h[o], 0.f);
  float a[64];
#pragma unroll
  for (int o = 0; o < 64; o++) a[o] = b2s[o];
#pragma unroll
  for (int c = 0; c < 64; c++) {
    const float* wr = wm + 4608 + c * 64;
    float x = h[c];
#pragma unroll
    for (int o = 0; o < 64; o++) a[o] = fmaf(wr[o], x, a[o]);
  }
  NSMAX_STORE(xs)

  // ---- score path: 12 -> 64 relu -> 64
#pragma unroll
  for (int l = 0; l < 12; l++) xsc[l] *= (1.f / 6.f);
#pragma unroll
  for (int o = 0; o < 64; o++) h[o] = b1c[o];
#pragma unroll
  for (int c = 0; c < 12; c++) {
    const float* wr = wm + 8704 + c * 64;
    float x = xsc[c];
#pragma unroll
    for (int o = 0; o < 64; o++) h[o] = fmaf(wr[o], x, h[o]);
  }
#pragma unroll
  for (int o = 0; o < 64; o++) h[o] = fmaxf(h[o], 0.f);
#pragma unroll
  for (int o = 0; o < 64; o++) a[o] = b2c[o];
#pragma unroll
  for (int c = 0; c < 64; c++) {
    const float* wr = wm + 9472 + c * 64;
    float x = h[c];
#pragma unroll
    for (int o = 0; o < 64; o++) a[o] = fmaf(wr[o], x, a[o]);
  }
  NSMAX_STORE(xc)
}

// ---- merged big 3x3 conv v3: 2 rows x 16 oc per thread (og=4).
// grid 384 = hi(12: og*3+head)*32 + q*8 + rt.  Tile: 8 out rows x 64 cols.
// LDS 16ic x 10 rows x 72 stride (data at col 4..67, pads col 3 & 68) = 46 KB.
template <bool RELU>
__global__ __launch_bounds__(256) void k_conv3h(
    const float* __restrict__ in0, const float* __restrict__ in1,
    const float* __restrict__ in2, const float* __restrict__ w0,
    const float* __restrict__ w1, const float* __restrict__ w2,
    const float* __restrict__ bb0, const float* __restrict__ bb1,
    const float* __restrict__ bb2, float* __restrict__ o0,
    float* __restrict__ o1, float* __restrict__ o2) {
  __shared__ float tile[16 * 10 * 72];  // 46.1 KB -> 3 blocks/CU
  int b = blockIdx.x;
  int hi = b >> 5;  // og*3 + head, og in 0..3
  int og = hi / 3;
  int head = hi - og * 3;
  int q = (b >> 3) & 3;
  int rt = b & 7;
  const float* in = head == 0 ? in0 : head == 1 ? in1 : in2;
  const float* wT = head == 0 ? w0 : head == 1 ? w1 : w2;
  const float* bb = head == 0 ? bb0 : head == 1 ? bb1 : bb2;
  float* outp = head == 0 ? o0 : head == 1 ? o1 : o2;

  int t = threadIdx.x;
  int w = t & 63;
  int wr = t >> 6;       // 0..3 (wave-uniform): thread rows 2wr, 2wr+1
  int lane4 = t & 15;    // staging: float4 col
  int rgrp = t >> 4;     // staging: 16 rows/pass
  float acc[2][16];
#pragma unroll
  for (int pr = 0; pr < 2; pr++)
#pragma unroll
    for (int o = 0; o < 16; o++) acc[pr][o] = 0.f;
  const float* inq = in + (size_t)q * 64 * HW;

  for (int icc = 0; icc < 4; icc++) {
    __syncthreads();
    // edge pads (rows 0..159): col 3 (img -1) and col 68 (img 64)
    if (t < 160) { tile[t * 72 + 3] = 0.f; tile[t * 72 + 68] = 0.f; }
    // stage 16 ic x 10 rows x 64 cols as float4
#pragma unroll
    for (int p = 0; p < 10; p++) {
      int idx = p * 16 + rgrp;  // 0..159
      int ch = idx / 10;
      int r = idx - ch * 10;
      int grow = rt * 8 + r - 1;
      float4 val = make_float4(0.f, 0.f, 0.f, 0.f);
      if (grow >= 0 && grow < 64)
        val = *(const float4*)(inq + (size_t)(icc * 16 + ch) * HW + grow * 64 +
                               lane4 * 4);
      *(float4*)(tile + idx * 72 + 4 + lane4 * 4) = val;
    }
    __syncthreads();
#pragma unroll 2
    for (int ic = 0; ic < 16; ic++) {
      // x window: 4 tile rows x 3 cols
      float xv[4][3];
      const float* tb = tile + (ic * 10 + wr * 2) * 72 + w + 3;
#pragma unroll
      for (int rr = 0; rr < 4; rr++)
#pragma unroll
        for (int dc = 0; dc < 3; dc++) xv[rr][dc] = tb[rr * 72 + dc];
      const float* wb = wT + (size_t)(icc * 16 + ic) * 9 * 64 + og * 16;
#pragma unroll
      for (int dr = 0; dr < 3; dr++)
#pragma unroll
        for (int dc = 0; dc < 3; dc++) {
          const float* wv = wb + (dr * 3 + dc) * 64;
#pragma unroll
          for (int o = 0; o < 16; o++) {
            float wj = wv[o];
            acc[0][o] = fmaf(wj, xv[0 + dr][dc], acc[0][o]);
            acc[1][o] = fmaf(wj, xv[1 + dr][dc], acc[1][o]);
          }
        }
    }
  }
#pragma unroll
  for (int pr = 0; pr < 2; pr++) {
    int orow = rt * 8 + wr * 2 + pr;
#pragma unroll
    for (int o = 0; o < 16; o++) {
      float rz = acc[pr][o] + bb[og * 16 + o];
      if (RELU) rz = fmaxf(rz, 0.f);
      outp[((size_t)q * 64 + og * 16 + o) * HW + orow * 64 + w] = rz;
    }
  }
}

// ---- merged small 3x3 conv (heads: OC=1,2,1), 1-row blocks ----
__global__ __launch_bounds__(256) void k_convSh(
    const float* __restrict__ in0, const float* __restrict__ in1,
    const float* __restrict__ in2, const float* __restrict__ wt0,
    const float* __restrict__ wt1, const float* __restrict__ wt2,
    const float* __restrict__ bb0, const float* __restrict__ bb1,
    const float* __restrict__ bb2, float* __restrict__ o0,
    float* __restrict__ o1, float* __restrict__ o2) {
  __shared__ float tile[64 * 3 * 66];  // 50.7 KB
  __shared__ float red[4 * 2 * 64];
  int b = blockIdx.x;  // 768 = head*256 + q*64 + row
  int head = b >> 8;
  int q = (b >> 6) & 3;
  int row = b & 63;
  const float* in = head == 0 ? in0 : head == 1 ? in1 : in2;
  const float* wt = head == 0 ? wt0 : head == 1 ? wt1 : wt2;
  const float* bb = head == 0 ? bb0 : head == 1 ? bb1 : bb2;
  float* outp = head == 0 ? o0 : head == 1 ? o1 : o2;
  int noc = (head == 1) ? 2 : 1;

  int t = threadIdx.x;
  int w = t & 63;
  int sub = t >> 6;
  if (t < 192) { tile[t * 66] = 0.f; tile[t * 66 + 65] = 0.f; }
  __syncthreads();
  const float* inq = in + (size_t)q * 64 * HW;
#pragma unroll
  for (int i = 0; i < 48; i++) {
    int idx = i * 4 + sub;
    int ic = idx / 3;
    int r = idx - ic * 3;
    int grow = row + r - 1;
    float val = 0.f;
    if (grow >= 0 && grow < 64) val = inq[(size_t)ic * HW + grow * 64 + w];
    tile[idx * 66 + 1 + w] = val;
  }
  __syncthreads();
  float acc0 = 0.f, acc1 = 0.f;
#pragma unroll 4
  for (int i = 0; i < 16; i++) {
    int ic = sub * 16 + i;
    float x[9];
#pragma unroll
    for (int dr = 0; dr < 3; dr++)
#pragma unroll
      for (int dc = 0; dc < 3; dc++)
        x[dr * 3 + dc] = tile[(ic * 3 + dr) * 66 + w + dc];
    const float* wb = wt + (size_t)ic * 9;
#pragma unroll
    for (int j = 0; j < 9; j++) acc0 += wb[j] * x[j];
    if (noc == 2) {
      const float* wb1 = wt + 576 + (size_t)ic * 9;
#pragma unroll
      for (int j = 0; j < 9; j++) acc1 += wb1[j] * x[j];
    }
  }
  red[(sub * 2 + 0) * 64 + w] = acc0;
  if (noc == 2) red[(sub * 2 + 1) * 64 + w] = acc1;
  __syncthreads();
  if (t < 128) {
    int o = t >> 6;
    if (o < noc) {
      float s = red[(0 * 2 + o) * 64 + w] + red[(1 * 2 + o) * 64 + w] +
                red[(2 * 2 + o) * 64 + w] + red[(3 * 2 + o) * 64 + w] + bb[o];
      outp[((size_t)q * noc + o) * HW + row * 64 + w] = s;
    }
  }
}

// ---------------- final: argmax + pos/scl ----------------
__global__ __launch_bounds__(256) void k_final(const float* __restrict__ scores,
                                               const float* __restrict__ scales,
                                               const float* __restrict__ offsets,
                                               float* __restrict__ pos,
                                               float* __restrict__ sclo) {
  int q = blockIdx.x, t = threadIdx.x;
  float best = -3.4e38f;
  int bi = 1 << 30;
  for (int i = t; i < HW; i += 256) {
    float v = scores[q * HW + i];
    if (v > best) { best = v; bi = i; }
  }
  __shared__ float bv[256];
  __shared__ int bix[256];
  bv[t] = best;
  bix[t] = bi;
  __syncthreads();
  for (int s = 128; s > 0; s >>= 1) {
    if (t < s) {
      if (bv[t + s] > bv[t] || (bv[t + s] == bv[t] && bix[t + s] < bix[t])) {
        bv[t] = bv[t + s];
        bix[t] = bix[t + s];
      }
    }
    __syncthreads();
  }
  if (t == 0) {
    int sid = bix[0];
    int sy = sid >> 6, sx = sid & 63;
    float o0 = offsets[(q * 2 + 0) * HW + sid];
    float o1 = offsets[(q * 2 + 1) * HW + sid];
    pos[q * 2 + 0] = ((float)sx + o0 + 0.5f) * 8.f - 0.5f;
    pos[q * 2 + 1] = ((float)sy + o1 + 0.5f) * 8.f - 0.5f;
    sclo[q] = exp2f(scales[q * HW + sid]);
  }
}

extern "C" void kernel_launch(void* const* d_in, const int* in_sizes, int n_in,
                              void* d_out, int out_size, void* d_ws, size_t ws_size,
                              hipStream_t stream) {
  const float* corr = (const float*)d_in[0];
  const float* w1s = (const float*)d_in[1];
  const float* b1s = (const float*)d_in[2];
  const float* w2s = (const float*)d_in[3];
  const float* b2s = (const float*)d_in[4];
  const float* w1c = (const float*)d_in[5];
  const float* b1c = (const float*)d_in[6];
  const float* w2c = (const float*)d_in[7];
  const float* b2c = (const float*)d_in[8];

  float* out = (float*)d_out;
  float* pos = out;                   // (4,2)
  float* sclo = out + 8;              // (4,)
  float* scores = out + 12;           // (4,1,64,64)
  float* scales = out + 12 + 16384;   // (4,1,64,64)
  float* offsets = out + 12 + 32768;  // (4,2,64,64)

  char* ws = (char*)d_ws;
  float* st_scl = (float*)(ws + 0);       // 36 KB
  float* st_shf = (float*)(ws + 36864);   // 36 KB
  int* topidx = (int*)(ws + 73728);       // 1 MB
  float* rs = (float*)(ws + 1122304);     // 8.39 MB (dead after k_topk)
  float* vbuf = rs;                       // 18.87 MB, overlaps rs (ok)
  float* wT = (float*)(ws + 19996672);    // 884 KB (big-conv transposed w)
  float* wmT = (float*)(ws + 20881408);   // 54 KB (MLP transposed w)
  float* xs = (float*)(ws + 20971520);    // 4.19 MB
  float* xc = (float*)(ws + 25165824);    // 4.19 MB  (total 29.4 MB)
  // t1/t2 reuse dead regions (stream-ordered):
  float* t1s = vbuf;                         // vbuf dead after k_mlpf
  float* t1o = (float*)((char*)vbuf + 4194304);
  float* t1c = (float*)((char*)vbuf + 8388608);
  float* t2c = (float*)((char*)vbuf + 12582912);
  float* t2s = xs;                           // xs dead after conv layer 1
  float* t2o = xc;                           // xc dead after conv layer 1

  k_stats_wx<<<9365, 256, 0, stream>>>(
      corr, st_scl, st_shf, (const float*)d_in[9], (const float*)d_in[11],
      (const float*)d_in[15], (const float*)d_in[17], (const float*)d_in[21],
      (const float*)d_in[23], wT, w1s, w2s, w1c, w2c, wmT);
  k_refscore<<<2048, 256, 0, stream>>>(corr, st_scl, st_shf, rs);
  k_topk<<<256, 256, 0, stream>>>(rs, topidx);
  k_gather<<<4608, 256, 0, stream>>>(corr, st_scl, st_shf, topidx, vbuf);
  k_mlpf<<<256, 256, 0, stream>>>(vbuf, wmT, b1s, b2s, b1c, b2c, xs, xc);
  // conv layer 1 (all heads): xs->t1s, xc->t1o, xc->t1c
  k_conv3h<true><<<384, 256, 0, stream>>>(
      xs, xc, xc, wT, wT + 2 * 36864, wT + 4 * 36864,
      (const float*)d_in[10], (const float*)d_in[16], (const float*)d_in[22],
      t1s, t1o, t1c);
  // conv layer 2 (all heads): t1*->t2*
  k_conv3h<true><<<384, 256, 0, stream>>>(
      t1s, t1o, t1c, wT + 1 * 36864, wT + 3 * 36864, wT + 5 * 36864,
      (const float*)d_in[12], (const float*)d_in[18], (const float*)d_in[24],
      t2s, t2o, t2c);
  // conv layer 3 (all heads): t2* -> scales/offsets/scores
  k_convSh<<<768, 256, 0, stream>>>(
      t2s, t2o, t2c, (const float*)d_in[13], (const float*)d_in[19],
      (const float*)d_in[25], (const float*)d_in[14], (const float*)d_in[20],
      (const float*)d_in[26], scales, offsets, scores);

  k_final<<<4, 256, 0, stream>>>(scores, scales, offsets, pos, sclo);
}

// Round 5
// 600.513 us; speedup vs baseline: 1.2505x; 1.0872x over previous
//
#include <hip/hip_runtime.h>

#define HW 4096

// ------- kernel A: fused instance-norm stats + ref_score (1 HBM pass over corr)
// blocks 0..511: one (q,r,ns) group each (18 ch x 4096 px = 295 KB).
//   pass 1: per-channel sum/sumsq (reg acc + xor-shuffle + LDS combine)
//   pass 2: re-read (L2/L3-hot) -> rs = mean_c(x*scl+shf)/18
// blocks 512..660: weight transposes (conv + MLP), independent work.
__global__ __launch_bounds__(256) void k_statsrs(
    const float* __restrict__ corr, float* __restrict__ scl,
    float* __restrict__ shf, float* __restrict__ rs,
    const float* __restrict__ p0, const float* __restrict__ p1,
    const float* __restrict__ p2, const float* __restrict__ p3,
    const float* __restrict__ p4, const float* __restrict__ p5,
    float* __restrict__ wT, const float* __restrict__ w1s,
    const float* __restrict__ w2s, const float* __restrict__ w1c,
    const float* __restrict__ w2c, float* __restrict__ wm) {
  int t = threadIdx.x;
  if (blockIdx.x >= 512) {
    int b = blockIdx.x - 512;  // 96 conv chunks + 53 mlp chunks
    if (b < 96) {
      int arr = b >> 4;
      int chunk = b & 15;
      const float* src = (arr == 0) ? p0
                         : (arr == 1) ? p1
                         : (arr == 2) ? p2
                         : (arr == 3) ? p3
                         : (arr == 4) ? p4 : p5;
      float* dst = wT + arr * 36864;
#pragma unroll
      for (int i = 0; i < 9; i++) {
        int e = chunk * 2304 + i * 256 + t;  // 0..36863
        int oc = e / 576;
        int rem = e - oc * 576;  // ic*9+j
        dst[rem * 64 + oc] = src[e];
      }
    } else {
      int i = (b - 96) * 256 + t;
      if (i < 4608) {
        int c = i >> 6, o = i & 63;
        wm[i] = w1s[o * 72 + c];
      } else if (i < 8704) {
        int j = i - 4608;
        int c = j >> 6, o = j & 63;
        wm[i] = w2s[o * 64 + c];
      } else if (i < 9472) {
        int j = i - 8704;
        int c = j >> 6, o = j & 63;
        wm[i] = w1c[o * 12 + c];
      } else if (i < 13568) {
        int j = i - 9472;
        int c = j >> 6, o = j & 63;
        wm[i] = w2c[o * 64 + c];
      }
    }
    return;
  }
  int g = blockIdx.x;  // (q*32+r)*4+ns
  const float4* p = (const float4*)(corr + (size_t)g * 18 * HW);

  // ---- pass 1: per-channel stats, 18 reg accumulators (static idx only)
  float s[18], s2[18];
#pragma unroll
  for (int c = 0; c < 18; c++) { s[c] = 0.f; s2[c] = 0.f; }
#pragma unroll
  for (int c = 0; c < 18; c++) {
#pragma unroll
    for (int i = 0; i < 4; i++) {
      float4 v = p[(c << 10) + (i << 8) + t];
      s[c] += v.x + v.y + v.z + v.w;
      s2[c] += v.x * v.x + v.y * v.y + v.z * v.z + v.w * v.w;
    }
  }
#pragma unroll
  for (int c = 0; c < 18; c++) {
#pragma unroll
    for (int o = 1; o < 64; o <<= 1) {
      s[c] += __shfl_xor(s[c], o, 64);
      s2[c] += __shfl_xor(s2[c], o, 64);
    }
  }
  __shared__ float lds_s[4][18], lds_s2[4][18];
  __shared__ float lds_scl[18], lds_shf[18];
  int wid = t >> 6;
  int ln = t & 63;
  if (ln < 18) {
    float vs = 0.f, vs2 = 0.f;
#pragma unroll
    for (int c = 0; c < 18; c++) {
      vs = (ln == c) ? s[c] : vs;
      vs2 = (ln == c) ? s2[c] : vs2;
    }
    lds_s[wid][ln] = vs;
    lds_s2[wid][ln] = vs2;
  }
  __syncthreads();
  if (t < 18) {
    float S = lds_s[0][t] + lds_s[1][t] + lds_s[2][t] + lds_s[3][t];
    float S2 = lds_s2[0][t] + lds_s2[1][t] + lds_s2[2][t] + lds_s2[3][t];
    float m = S * (1.f / HW);
    float var = S2 * (1.f / HW) - m * m;
    float r = rsqrtf(var + 1e-5f);
    scl[g * 18 + t] = r;
    shf[g * 18 + t] = -m * r;
    lds_scl[t] = r;
    lds_shf[t] = -m * r;
  }
  __syncthreads();

  // ---- pass 2: re-read (cache-hot), rs = (sum_c x*scl + sum_c shf)/18
  float shsum = 0.f;
#pragma unroll
  for (int c = 0; c < 18; c++) shsum += lds_shf[c];
  const float inv = 1.f / 18.f;
#pragma unroll
  for (int i = 0; i < 4; i++) {
    float4 acc = make_float4(0.f, 0.f, 0.f, 0.f);
#pragma unroll
    for (int c = 0; c < 18; c++) {
      float4 v = p[(c << 10) + (i << 8) + t];
      float sc = lds_scl[c];
      acc.x = fmaf(v.x, sc, acc.x);
      acc.y = fmaf(v.y, sc, acc.y);
      acc.z = fmaf(v.z, sc, acc.z);
      acc.w = fmaf(v.w, sc, acc.w);
    }
    float4 o;
    o.x = (acc.x + shsum) * inv;
    o.y = (acc.y + shsum) * inv;
    o.z = (acc.z + shsum) * inv;
    o.w = (acc.w + shsum) * inv;
    ((float4*)(rs + (size_t)g * HW))[(i << 8) + t] = o;
  }
}

// ---------------- kernel C: top-4 of 32, LDS-staged ----------------
__global__ __launch_bounds__(256) void k_topk(const float* __restrict__ rs,
                                              int* __restrict__ topidx) {
  __shared__ float st[32 * 256];  // 32 KB
  int b = blockIdx.x;             // 256 = q*4ns*16pxc
  int pxc = b & 15;
  int ns = (b >> 4) & 3;
  int q = b >> 6;
  int t = threadIdx.x;
  int pxb = pxc * 256;
#pragma unroll 8
  for (int r = 0; r < 32; r++)
    st[r * 256 + t] = rs[((q * 32 + r) * 4 + ns) * HW + pxb + t];
  __syncthreads();
  float v[32];
#pragma unroll
  for (int r = 0; r < 32; r++) v[r] = st[r * 256 + t];
  unsigned mask = 0;
  int sel[4];
#pragma unroll
  for (int k = 0; k < 4; k++) {
    float best = -3.4e38f;
    int bi = 0;
#pragma unroll
    for (int r = 0; r < 32; r++) {
      bool take = (!(mask & (1u << r))) && (v[r] > best);
      best = take ? v[r] : best;
      bi = take ? r : bi;
    }
    sel[k] = bi;
    mask |= (1u << bi);
  }
  ((int4*)topidx)[(q * 4 + ns) * HW + pxb + t] =
      make_int4(sel[0], sel[1], sel[2], sel[3]);
}

// -------- kernel D1: high-occupancy streaming gather+norm -> vbuf ----------
__global__ __launch_bounds__(256) void k_gather(const float* __restrict__ corr,
                                                const float* __restrict__ scl,
                                                const float* __restrict__ shf,
                                                const int* __restrict__ topidx,
                                                float* __restrict__ vbuf) {
  __shared__ float ls[32], lsh[32];
  int b = blockIdx.x;  // 4608 = q x pxc x ns x c
  int c = b % 18;
  int rest = b / 18;
  int ns = rest & 3;
  int pxc = (rest >> 2) & 15;
  int q = rest >> 6;
  int t = threadIdx.x;
  int px = pxc * 256 + t;

  if (t < 32) {
    int g = q * 2304 + t * 72 + ns * 18 + c;
    ls[t] = scl[g];
    lsh[t] = shf[g];
  }
  int4 ti = ((const int4*)topidx)[(q * 4 + ns) * HW + px];
  int rk0 = ti.x, rk1 = ti.y, rk2 = ti.z, rk3 = ti.w;
  __syncthreads();

  const float* base = corr + (size_t)(((q * 32) * 4 + ns) * 18 + c) * HW + px;
  float v0 = 0.f, v1 = 0.f, v2 = 0.f, v3 = 0.f;
#pragma unroll
  for (int r = 0; r < 32; r++) {
    float x = base[(size_t)r * 72 * HW];
    v0 = (rk0 == r) ? x : v0;
    v1 = (rk1 == r) ? x : v1;
    v2 = (rk2 == r) ? x : v2;
    v3 = (rk3 == r) ? x : v3;
  }
  v0 = v0 * ls[rk0] + lsh[rk0];
  v1 = v1 * ls[rk1] + lsh[rk1];
  v2 = v2 * ls[rk2] + lsh[rk2];
  v3 = v3 * ls[rk3] + lsh[rk3];
  size_t ob = (size_t)((q * 4 + ns) * 72 + c) * HW + px;
  vbuf[ob] = v0;
  vbuf[ob + 18 * HW] = v1;
  vbuf[ob + 36 * HW] = v2;
  vbuf[ob + 54 * HW] = v3;
}

// ---- kernel D2 v2: both MLPs, output-split 4x for occupancy.
// grid 1024 = q(4) x pxg(256 groups of 16 px). 256 thr = oseg(4) x ns(4) x pxi(16).
// Each thread computes 16 of 64 channels; h exchanged via LDS for layer 2.
// LDS: lx 18KB + lh 16KB + lxsc 3KB = 37.9KB -> 4 blocks/CU, 4 waves/SIMD.
__global__ __launch_bounds__(256, 4) void k_mlp2(
    const float* __restrict__ vbuf, const float* __restrict__ wm,
    const float* __restrict__ b1s, const float* __restrict__ b2s,
    const float* __restrict__ b1c, const float* __restrict__ b2c,
    float* __restrict__ xs, float* __restrict__ xc) {
  __shared__ float lx[72 * 64];   // x staging; reused as a-staging for ns-max
  __shared__ float lh[64 * 64];   // hidden exchange
  __shared__ float lxsc[12 * 64]; // level means (score-path input)
  int blk = blockIdx.x;
  int q = blk >> 8, pxg = blk & 255;
  int t = threadIdx.x;
  int wi = t & 63;       // ns*16 + pxi
  int oseg = t >> 6;     // wave-uniform: output segment (16 ch)
  int px0 = pxg * 16;

  // stage x: wave w of iter j loads channel c=4j+w for all 64 (ns,pxi)
  const float* vq = vbuf + (size_t)(q * 4) * 72 * HW + px0;
#pragma unroll
  for (int j = 0; j < 18; j++) {
    int e = j * 256 + t;
    int c = e >> 6;
    int w2 = e & 63;
    int nns = w2 >> 4, ppx = w2 & 15;
    lx[c * 64 + w2] = vq[(size_t)(nns * 72 + c) * HW + ppx];
  }
  __syncthreads();

  // level means: lxsc[l][wi] = mean of 6 consecutive channels
#pragma unroll
  for (int m = 0; m < 3; m++) {
    int idx = m * 256 + t;  // 0..767
    int l = idx >> 6, w2 = idx & 63;
    float sm = 0.f;
#pragma unroll
    for (int j = 0; j < 6; j++) sm += lx[(l * 6 + j) * 64 + w2];
    lxsc[l * 64 + w2] = sm * (1.f / 6.f);
  }

  // ---- scale path layer 1: 72 -> 16 (this thread's segment)
  float h[16];
  const float* bp1 = b1s + oseg * 16;
#pragma unroll
  for (int o = 0; o < 16; o++) h[o] = bp1[o];
#pragma unroll
  for (int c = 0; c < 72; c++) {
    float x = lx[c * 64 + wi];
    const float* wr = wm + c * 64 + oseg * 16;  // wave-uniform -> s_load
#pragma unroll
    for (int o = 0; o < 16; o++) h[o] = fmaf(wr[o], x, h[o]);
  }
#pragma unroll
  for (int o = 0; o < 16; o++) lh[(oseg * 16 + o) * 64 + wi] = fmaxf(h[o], 0.f);
  __syncthreads();

  // ---- scale path layer 2: 64 -> 16
  float a[16];
  const float* bp2 = b2s + oseg * 16;
#pragma unroll
  for (int o = 0; o < 16; o++) a[o] = bp2[o];
#pragma unroll
  for (int c = 0; c < 64; c++) {
    float x = lh[c * 64 + wi];
    const float* wr = wm + 4608 + c * 64 + oseg * 16;
#pragma unroll
    for (int o = 0; o < 16; o++) a[o] = fmaf(wr[o], x, a[o]);
  }
  // stage a into lx (dead) for ns-max
#pragma unroll
  for (int o = 0; o < 16; o++) lx[(oseg * 16 + o) * 64 + wi] = a[o];
  __syncthreads();

  // ns-max + store xs: 1024 (oc,px) results, 4 per thread
#pragma unroll
  for (int m = 0; m < 4; m++) {
    int idx = m * 256 + t;
    int oc = idx >> 4, ppx = idx & 15;
    float v = lx[oc * 64 + ppx];
    v = fmaxf(v, lx[oc * 64 + 16 + ppx]);
    v = fmaxf(v, lx[oc * 64 + 32 + ppx]);
    v = fmaxf(v, lx[oc * 64 + 48 + ppx]);
    xs[(size_t)(q * 64 + oc) * HW + px0 + ppx] = v;
  }

  // ---- score path layer 1: 12 -> 16
  const float* bc1 = b1c + oseg * 16;
#pragma unroll
  for (int o = 0; o < 16; o++) h[o] = bc1[o];
#pragma unroll
  for (int c = 0; c < 12; c++) {
    float x = lxsc[c * 64 + wi];
    const float* wr = wm + 8704 + c * 64 + oseg * 16;
#pragma unroll
    for (int o = 0; o < 16; o++) h[o] = fmaf(wr[o], x, h[o]);
  }
  __syncthreads();  // all scale-path lh reads + lx max-reads done
#pragma unroll
  for (int o = 0; o < 16; o++) lh[(oseg * 16 + o) * 64 + wi] = fmaxf(h[o], 0.f);
  __syncthreads();

  // ---- score path layer 2: 64 -> 16
  const float* bc2 = b2c + oseg * 16;
#pragma unroll
  for (int o = 0; o < 16; o++) a[o] = bc2[o];
#pragma unroll
  for (int c = 0; c < 64; c++) {
    float x = lh[c * 64 + wi];
    const float* wr = wm + 9472 + c * 64 + oseg * 16;
#pragma unroll
    for (int o = 0; o < 16; o++) a[o] = fmaf(wr[o], x, a[o]);
  }
#pragma unroll
  for (int o = 0; o < 16; o++) lx[(oseg * 16 + o) * 64 + wi] = a[o];
  __syncthreads();

  // ns-max + store xc
#pragma unroll
  for (int m = 0; m < 4; m++) {
    int idx = m * 256 + t;
    int oc = idx >> 4, ppx = idx & 15;
    float v = lx[oc * 64 + ppx];
    v = fmaxf(v, lx[oc * 64 + 16 + ppx]);
    v = fmaxf(v, lx[oc * 64 + 32 + ppx]);
    v = fmaxf(v, lx[oc * 64 + 48 + ppx]);
    xc[(size_t)(q * 64 + oc) * HW + px0 + ppx] = v;
  }
}

// ---- merged big 3x3 conv v3: 2 rows x 16 oc per thread (og=4).
// grid 384 = hi(12: og*3+head)*32 + q*8 + rt.  Tile: 8 out rows x 64 cols.
// LDS 16ic x 10 rows x 72 stride (data at col 4..67, pads col 3 & 68) = 46 KB.
template <bool RELU>
__global__ __launch_bounds__(256) void k_conv3h(
    const float* __restrict__ in0, const float* __restrict__ in1,
    const float* __restrict__ in2, const float* __restrict__ w0,
    const float* __restrict__ w1, const float* __restrict__ w2,
    const float* __restrict__ bb0, const float* __restrict__ bb1,
    const float* __restrict__ bb2, float* __restrict__ o0,
    float* __restrict__ o1, float* __restrict__ o2) {
  __shared__ float tile[16 * 10 * 72];  // 46.1 KB -> 3 blocks/CU
  int b = blockIdx.x;
  int hi = b >> 5;  // og*3 + head, og in 0..3
  int og = hi / 3;
  int head = hi - og * 3;
  int q = (b >> 3) & 3;
  int rt = b & 7;
  const float* in = head == 0 ? in0 : head == 1 ? in1 : in2;
  const float* wT = head == 0 ? w0 : head == 1 ? w1 : w2;
  const float* bb = head == 0 ? bb0 : head == 1 ? bb1 : bb2;
  float* outp = head == 0 ? o0 : head == 1 ? o1 : o2;

  int t = threadIdx.x;
  int w = t & 63;
  int wr = t >> 6;       // 0..3 (wave-uniform): thread rows 2wr, 2wr+1
  int lane4 = t & 15;    // staging: float4 col
  int rgrp = t >> 4;     // staging: 16 rows/pass
  float acc[2][16];
#pragma unroll
  for (int pr = 0; pr < 2; pr++)
#pragma unroll
    for (int o = 0; o < 16; o++) acc[pr][o] = 0.f;
  const float* inq = in + (size_t)q * 64 * HW;

  for (int icc = 0; icc < 4; icc++) {
    __syncthreads();
    // edge pads (rows 0..159): col 3 (img -1) and col 68 (img 64)
    if (t < 160) { tile[t * 72 + 3] = 0.f; tile[t * 72 + 68] = 0.f; }
    // stage 16 ic x 10 rows x 64 cols as float4
#pragma unroll
    for (int p = 0; p < 10; p++) {
      int idx = p * 16 + rgrp;  // 0..159
      int ch = idx / 10;
      int r = idx - ch * 10;
      int grow = rt * 8 + r - 1;
      float4 val = make_float4(0.f, 0.f, 0.f, 0.f);
      if (grow >= 0 && grow < 64)
        val = *(const float4*)(inq + (size_t)(icc * 16 + ch) * HW + grow * 64 +
                               lane4 * 4);
      *(float4*)(tile + idx * 72 + 4 + lane4 * 4) = val;
    }
    __syncthreads();
#pragma unroll 2
    for (int ic = 0; ic < 16; ic++) {
      // x window: 4 tile rows x 3 cols
      float xv[4][3];
      const float* tb = tile + (ic * 10 + wr * 2) * 72 + w + 3;
#pragma unroll
      for (int rr = 0; rr < 4; rr++)
#pragma unroll
        for (int dc = 0; dc < 3; dc++) xv[rr][dc] = tb[rr * 72 + dc];
      const float* wb = wT + (size_t)(icc * 16 + ic) * 9 * 64 + og * 16;
#pragma unroll
      for (int dr = 0; dr < 3; dr++)
#pragma unroll
        for (int dc = 0; dc < 3; dc++) {
          const float* wv = wb + (dr * 3 + dc) * 64;
#pragma unroll
          for (int o = 0; o < 16; o++) {
            float wj = wv[o];
            acc[0][o] = fmaf(wj, xv[0 + dr][dc], acc[0][o]);
            acc[1][o] = fmaf(wj, xv[1 + dr][dc], acc[1][o]);
          }
        }
    }
  }
#pragma unroll
  for (int pr = 0; pr < 2; pr++) {
    int orow = rt * 8 + wr * 2 + pr;
#pragma unroll
    for (int o = 0; o < 16; o++) {
      float rz = acc[pr][o] + bb[og * 16 + o];
      if (RELU) rz = fmaxf(rz, 0.f);
      outp[((size_t)q * 64 + og * 16 + o) * HW + orow * 64 + w] = rz;
    }
  }
}

// ---- merged small 3x3 conv (heads: OC=1,2,1), 1-row blocks ----
__global__ __launch_bounds__(256) void k_convSh(
    const float* __restrict__ in0, const float* __restrict__ in1,
    const float* __restrict__ in2, const float* __restrict__ wt0,
    const float* __restrict__ wt1, const float* __restrict__ wt2,
    const float* __restrict__ bb0, const float* __restrict__ bb1,
    const float* __restrict__ bb2, float* __restrict__ o0,
    float* __restrict__ o1, float* __restrict__ o2) {
  __shared__ float tile[64 * 3 * 66];  // 50.7 KB
  __shared__ float red[4 * 2 * 64];
  int b = blockIdx.x;  // 768 = head*256 + q*64 + row
  int head = b >> 8;
  int q = (b >> 6) & 3;
  int row = b & 63;
  const float* in = head == 0 ? in0 : head == 1 ? in1 : in2;
  const float* wt = head == 0 ? wt0 : head == 1 ? wt1 : wt2;
  const float* bb = head == 0 ? bb0 : head == 1 ? bb1 : bb2;
  float* outp = head == 0 ? o0 : head == 1 ? o1 : o2;
  int noc = (head == 1) ? 2 : 1;

  int t = threadIdx.x;
  int w = t & 63;
  int sub = t >> 6;
  if (t < 192) { tile[t * 66] = 0.f; tile[t * 66 + 65] = 0.f; }
  __syncthreads();
  const float* inq = in + (size_t)q * 64 * HW;
#pragma unroll
  for (int i = 0; i < 48; i++) {
    int idx = i * 4 + sub;
    int ic = idx / 3;
    int r = idx - ic * 3;
    int grow = row + r - 1;
    float val = 0.f;
    if (grow >= 0 && grow < 64) val = inq[(size_t)ic * HW + grow * 64 + w];
    tile[idx * 66 + 1 + w] = val;
  }
  __syncthreads();
  float acc0 = 0.f, acc1 = 0.f;
#pragma unroll 4
  for (int i = 0; i < 16; i++) {
    int ic = sub * 16 + i;
    float x[9];
#pragma unroll
    for (int dr = 0; dr < 3; dr++)
#pragma unroll
      for (int dc = 0; dc < 3; dc++)
        x[dr * 3 + dc] = tile[(ic * 3 + dr) * 66 + w + dc];
    const float* wb = wt + (size_t)ic * 9;
#pragma unroll
    for (int j = 0; j < 9; j++) acc0 += wb[j] * x[j];
    if (noc == 2) {
      const float* wb1 = wt + 576 + (size_t)ic * 9;
#pragma unroll
      for (int j = 0; j < 9; j++) acc1 += wb1[j] * x[j];
    }
  }
  red[(sub * 2 + 0) * 64 + w] = acc0;
  if (noc == 2) red[(sub * 2 + 1) * 64 + w] = acc1;
  __syncthreads();
  if (t < 128) {
    int o = t >> 6;
    if (o < noc) {
      float s = red[(0 * 2 + o) * 64 + w] + red[(1 * 2 + o) * 64 + w] +
                red[(2 * 2 + o) * 64 + w] + red[(3 * 2 + o) * 64 + w] + bb[o];
      outp[((size_t)q * noc + o) * HW + row * 64 + w] = s;
    }
  }
}

// ---------------- final: argmax + pos/scl ----------------
__global__ __launch_bounds__(256) void k_final(const float* __restrict__ scores,
                                               const float* __restrict__ scales,
                                               const float* __restrict__ offsets,
                                               float* __restrict__ pos,
                                               float* __restrict__ sclo) {
  int q = blockIdx.x, t = threadIdx.x;
  float best = -3.4e38f;
  int bi = 1 << 30;
  for (int i = t; i < HW; i += 256) {
    float v = scores[q * HW + i];
    if (v > best) { best = v; bi = i; }
  }
  __shared__ float bv[256];
  __shared__ int bix[256];
  bv[t] = best;
  bix[t] = bi;
  __syncthreads();
  for (int s = 128; s > 0; s >>= 1) {
    if (t < s) {
      if (bv[t + s] > bv[t] || (bv[t + s] == bv[t] && bix[t + s] < bix[t])) {
        bv[t] = bv[t + s];
        bix[t] = bix[t + s];
      }
    }
    __syncthreads();
  }
  if (t == 0) {
    int sid = bix[0];
    int sy = sid >> 6, sx = sid & 63;
    float o0 = offsets[(q * 2 + 0) * HW + sid];
    float o1 = offsets[(q * 2 + 1) * HW + sid];
    pos[q * 2 + 0] = ((float)sx + o0 + 0.5f) * 8.f - 0.5f;
    pos[q * 2 + 1] = ((float)sy + o1 + 0.5f) * 8.f - 0.5f;
    sclo[q] = exp2f(scales[q * HW + sid]);
  }
}

extern "C" void kernel_launch(void* const* d_in, const int* in_sizes, int n_in,
                              void* d_out, int out_size, void* d_ws, size_t ws_size,
                              hipStream_t stream) {
  const float* corr = (const float*)d_in[0];
  const float* w1s = (const float*)d_in[1];
  const float* b1s = (const float*)d_in[2];
  const float* w2s = (const float*)d_in[3];
  const float* b2s = (const float*)d_in[4];
  const float* w1c = (const float*)d_in[5];
  const float* b1c = (const float*)d_in[6];
  const float* w2c = (const float*)d_in[7];
  const float* b2c = (const float*)d_in[8];

  float* out = (float*)d_out;
  float* pos = out;                   // (4,2)
  float* sclo = out + 8;              // (4,)
  float* scores = out + 12;           // (4,1,64,64)
  float* scales = out + 12 + 16384;   // (4,1,64,64)
  float* offsets = out + 12 + 32768;  // (4,2,64,64)

  char* ws = (char*)d_ws;
  float* st_scl = (float*)(ws + 0);       // 36 KB
  float* st_shf = (float*)(ws + 36864);   // 36 KB
  int* topidx = (int*)(ws + 73728);       // 1 MB
  float* rs = (float*)(ws + 1122304);     // 8.39 MB (dead after k_topk)
  float* vbuf = rs;                       // 18.87 MB, overlaps rs (ok)
  float* wT = (float*)(ws + 19996672);    // 884 KB (big-conv transposed w)
  float* wmT = (float*)(ws + 20881408);   // 54 KB (MLP transposed w)
  float* xs = (float*)(ws + 20971520);    // 4.19 MB
  float* xc = (float*)(ws + 25165824);    // 4.19 MB  (total 29.4 MB)
  // t1/t2 reuse dead regions (stream-ordered):
  float* t1s = vbuf;                         // vbuf dead after k_mlp2
  float* t1o = (float*)((char*)vbuf + 4194304);
  float* t1c = (float*)((char*)vbuf + 8388608);
  float* t2c = (float*)((char*)vbuf + 12582912);
  float* t2s = xs;                           // xs dead after conv layer 1
  float* t2o = xc;                           // xc dead after conv layer 1

  k_statsrs<<<661, 256, 0, stream>>>(
      corr, st_scl, st_shf, rs, (const float*)d_in[9], (const float*)d_in[11],
      (const float*)d_in[15], (const float*)d_in[17], (const float*)d_in[21],
      (const float*)d_in[23], wT, w1s, w2s, w1c, w2c, wmT);
  k_topk<<<256, 256, 0, stream>>>(rs, topidx);
  k_gather<<<4608, 256, 0, stream>>>(corr, st_scl, st_shf, topidx, vbuf);
  k_mlp2<<<1024, 256, 0, stream>>>(vbuf, wmT, b1s, b2s, b1c, b2c, xs, xc);
  // conv layer 1 (all heads): xs->t1s, xc->t1o, xc->t1c
  k_conv3h<true><<<384, 256, 0, stream>>>(
      xs, xc, xc, wT, wT + 2 * 36864, wT + 4 * 36864,
      (const float*)d_in[10], (const float*)d_in[16], (const float*)d_in[22],
      t1s, t1o, t1c);
  // conv layer 2 (all heads): t1*->t2*
  k_conv3h<true><<<384, 256, 0, stream>>>(
      t1s, t1o, t1c, wT + 1 * 36864, wT + 3 * 36864, wT + 5 * 36864,
      (const float*)d_in[12], (const float*)d_in[18], (const float*)d_in[24],
      t2s, t2o, t2c);
  // conv layer 3 (all heads): t2* -> scales/offsets/scores
  k_convSh<<<768, 256, 0, stream>>>(
      t2s, t2o, t2c, (const float*)d_in[13], (const float*)d_in[19],
      (const float*)d_in[25], (const float*)d_in[14], (const float*)d_in[20],
      (const float*)d_in[26], scales, offsets, scores);

  k_final<<<4, 256, 0, stream>>>(scores, scales, offsets, pos, sclo);
}

// Round 6
// 600.166 us; speedup vs baseline: 1.2512x; 1.0006x over previous
//
#include <hip/hip_runtime.h>

#define HW 4096

// ------- kernel A: fused instance-norm stats + ref_score (1 HBM pass over corr)
// blocks 0..511: one (q,r,ns) group each (18 ch x 4096 px = 295 KB).
//   pass 1: per-channel sum/sumsq (reg acc + xor-shuffle + LDS combine)
//   pass 2: re-read (L2/L3-hot) -> rs = mean_c(x*scl+shf)/18
// blocks 512..660: weight transposes (conv + MLP), independent work.
__global__ __launch_bounds__(256) void k_statsrs(
    const float* __restrict__ corr, float* __restrict__ scl,
    float* __restrict__ shf, float* __restrict__ rs,
    const float* __restrict__ p0, const float* __restrict__ p1,
    const float* __restrict__ p2, const float* __restrict__ p3,
    const float* __restrict__ p4, const float* __restrict__ p5,
    float* __restrict__ wT, const float* __restrict__ w1s,
    const float* __restrict__ w2s, const float* __restrict__ w1c,
    const float* __restrict__ w2c, float* __restrict__ wm) {
  int t = threadIdx.x;
  if (blockIdx.x >= 512) {
    int b = blockIdx.x - 512;  // 96 conv chunks + 53 mlp chunks
    if (b < 96) {
      int arr = b >> 4;
      int chunk = b & 15;
      const float* src = (arr == 0) ? p0
                         : (arr == 1) ? p1
                         : (arr == 2) ? p2
                         : (arr == 3) ? p3
                         : (arr == 4) ? p4 : p5;
      float* dst = wT + arr * 36864;
#pragma unroll
      for (int i = 0; i < 9; i++) {
        int e = chunk * 2304 + i * 256 + t;  // 0..36863
        int oc = e / 576;
        int rem = e - oc * 576;  // ic*9+j
        dst[rem * 64 + oc] = src[e];
      }
    } else {
      int i = (b - 96) * 256 + t;
      if (i < 4608) {
        int c = i >> 6, o = i & 63;
        wm[i] = w1s[o * 72 + c];
      } else if (i < 8704) {
        int j = i - 4608;
        int c = j >> 6, o = j & 63;
        wm[i] = w2s[o * 64 + c];
      } else if (i < 9472) {
        int j = i - 8704;
        int c = j >> 6, o = j & 63;
        wm[i] = w1c[o * 12 + c];
      } else if (i < 13568) {
        int j = i - 9472;
        int c = j >> 6, o = j & 63;
        wm[i] = w2c[o * 64 + c];
      }
    }
    return;
  }
  int g = blockIdx.x;  // (q*32+r)*4+ns
  const float4* p = (const float4*)(corr + (size_t)g * 18 * HW);

  // ---- pass 1: per-channel stats, 18 reg accumulators (static idx only)
  float s[18], s2[18];
#pragma unroll
  for (int c = 0; c < 18; c++) { s[c] = 0.f; s2[c] = 0.f; }
#pragma unroll
  for (int c = 0; c < 18; c++) {
#pragma unroll
    for (int i = 0; i < 4; i++) {
      float4 v = p[(c << 10) + (i << 8) + t];
      s[c] += v.x + v.y + v.z + v.w;
      s2[c] += v.x * v.x + v.y * v.y + v.z * v.z + v.w * v.w;
    }
  }
#pragma unroll
  for (int c = 0; c < 18; c++) {
#pragma unroll
    for (int o = 1; o < 64; o <<= 1) {
      s[c] += __shfl_xor(s[c], o, 64);
      s2[c] += __shfl_xor(s2[c], o, 64);
    }
  }
  __shared__ float lds_s[4][18], lds_s2[4][18];
  __shared__ float lds_scl[18], lds_shf[18];
  int wid = t >> 6;
  int ln = t & 63;
  if (ln < 18) {
    float vs = 0.f, vs2 = 0.f;
#pragma unroll
    for (int c = 0; c < 18; c++) {
      vs = (ln == c) ? s[c] : vs;
      vs2 = (ln == c) ? s2[c] : vs2;
    }
    lds_s[wid][ln] = vs;
    lds_s2[wid][ln] = vs2;
  }
  __syncthreads();
  if (t < 18) {
    float S = lds_s[0][t] + lds_s[1][t] + lds_s[2][t] + lds_s[3][t];
    float S2 = lds_s2[0][t] + lds_s2[1][t] + lds_s2[2][t] + lds_s2[3][t];
    float m = S * (1.f / HW);
    float var = S2 * (1.f / HW) - m * m;
    float r = rsqrtf(var + 1e-5f);
    scl[g * 18 + t] = r;
    shf[g * 18 + t] = -m * r;
    lds_scl[t] = r;
    lds_shf[t] = -m * r;
  }
  __syncthreads();

  // ---- pass 2: re-read (cache-hot), rs = (sum_c x*scl + sum_c shf)/18
  float shsum = 0.f;
#pragma unroll
  for (int c = 0; c < 18; c++) shsum += lds_shf[c];
  const float inv = 1.f / 18.f;
#pragma unroll
  for (int i = 0; i < 4; i++) {
    float4 acc = make_float4(0.f, 0.f, 0.f, 0.f);
#pragma unroll
    for (int c = 0; c < 18; c++) {
      float4 v = p[(c << 10) + (i << 8) + t];
      float sc = lds_scl[c];
      acc.x = fmaf(v.x, sc, acc.x);
      acc.y = fmaf(v.y, sc, acc.y);
      acc.z = fmaf(v.z, sc, acc.z);
      acc.w = fmaf(v.w, sc, acc.w);
    }
    float4 o;
    o.x = (acc.x + shsum) * inv;
    o.y = (acc.y + shsum) * inv;
    o.z = (acc.z + shsum) * inv;
    o.w = (acc.w + shsum) * inv;
    ((float4*)(rs + (size_t)g * HW))[(i << 8) + t] = o;
  }
}

// ---------------- kernel C: top-4 of 32, LDS-staged ----------------
__global__ __launch_bounds__(256) void k_topk(const float* __restrict__ rs,
                                              int* __restrict__ topidx) {
  __shared__ float st[32 * 256];  // 32 KB
  int b = blockIdx.x;             // 256 = q*4ns*16pxc
  int pxc = b & 15;
  int ns = (b >> 4) & 3;
  int q = b >> 6;
  int t = threadIdx.x;
  int pxb = pxc * 256;
#pragma unroll 8
  for (int r = 0; r < 32; r++)
    st[r * 256 + t] = rs[((q * 32 + r) * 4 + ns) * HW + pxb + t];
  __syncthreads();
  float v[32];
#pragma unroll
  for (int r = 0; r < 32; r++) v[r] = st[r * 256 + t];
  unsigned mask = 0;
  int sel[4];
#pragma unroll
  for (int k = 0; k < 4; k++) {
    float best = -3.4e38f;
    int bi = 0;
#pragma unroll
    for (int r = 0; r < 32; r++) {
      bool take = (!(mask & (1u << r))) && (v[r] > best);
      best = take ? v[r] : best;
      bi = take ? r : bi;
    }
    sel[k] = bi;
    mask |= (1u << bi);
  }
  ((int4*)topidx)[(q * 4 + ns) * HW + pxb + t] =
      make_int4(sel[0], sel[1], sel[2], sel[3]);
}

// ---- kernel D: fused direct-gather + both MLPs, 512 thr, 8 osegs x 8 ch.
// grid 1024 = q(4) x pxg(256 groups of 16 px).
// thread = oseg(8) x ns(4) x pxi(16).  k = oseg>>1, ch-half = oseg&1.
// Each thread gathers its 9 (k-row, channel) values directly from corr
// (L3-resident, data-dependent addresses, all loads independent), normalizes,
// stages to LDS; MLP layers split 8 ways over output channels.
// LDS: lx 18KB + lh 16KB + lxsc 3KB = 37.4KB -> 4 blocks/CU = 32 waves/CU.
__global__ __launch_bounds__(512, 8) void k_mlp3(
    const float* __restrict__ corr, const float* __restrict__ scl,
    const float* __restrict__ shf, const int* __restrict__ topidx,
    const float* __restrict__ wm, const float* __restrict__ b1s,
    const float* __restrict__ b2s, const float* __restrict__ b1c,
    const float* __restrict__ b2c, float* __restrict__ xs,
    float* __restrict__ xc) {
  __shared__ float lx[72 * 64];    // gathered+normed x; later reused for a
  __shared__ float lh[64 * 64];    // hidden exchange
  __shared__ float lxsc[12 * 64];  // level means (score-path input)
  int blk = blockIdx.x;
  int q = blk >> 8, pxg = blk & 255;
  int t = threadIdx.x;
  int wi = t & 63;      // ns*16 + pxi
  int oseg = t >> 6;    // wave-uniform 0..7
  int ns = (t >> 4) & 3;
  int pxi = t & 15;
  int px = pxg * 16 + pxi;
  int k = oseg >> 1;        // wave-uniform knn slot
  int ch0 = (oseg & 1) * 9; // wave-uniform channel half

  int4 ti = ((const int4*)topidx)[(q * 4 + ns) * HW + px];
  int rk = (k == 0) ? ti.x : (k == 1) ? ti.y : (k == 2) ? ti.z : ti.w;
  int gidx = ((q * 32 + rk) * 4 + ns) * 18 + ch0;
  const float* cb = corr + (size_t)gidx * HW + px;
  const float* sb = scl + gidx;
  const float* hb = shf + gidx;
  float xv[9], sv[9], hv[9];
#pragma unroll
  for (int j = 0; j < 9; j++) xv[j] = cb[(size_t)j * HW];
#pragma unroll
  for (int j = 0; j < 9; j++) sv[j] = sb[j];
#pragma unroll
  for (int j = 0; j < 9; j++) hv[j] = hb[j];
#pragma unroll
  for (int j = 0; j < 9; j++)
    lx[(k * 18 + ch0 + j) * 64 + wi] = fmaf(xv[j], sv[j], hv[j]);
  __syncthreads();  // #1: lx complete

  // level means: lxsc[l][col], 768 entries over 512 threads
#pragma unroll
  for (int m = 0; m < 2; m++) {
    int idx = m * 512 + t;
    if (idx < 768) {
      int l = idx >> 6, w2 = idx & 63;
      float sm = 0.f;
#pragma unroll
      for (int j = 0; j < 6; j++) sm += lx[(l * 6 + j) * 64 + w2];
      lxsc[l * 64 + w2] = sm * (1.f / 6.f);
    }
  }

  // ---- scale path layer 1: 72 -> 8 (this thread's segment)
  float h[8];
  const float* bp1 = b1s + oseg * 8;
#pragma unroll
  for (int o = 0; o < 8; o++) h[o] = bp1[o];
#pragma unroll
  for (int c = 0; c < 72; c++) {
    float x = lx[c * 64 + wi];
    const float* wr = wm + c * 64 + oseg * 8;  // wave-uniform -> s_load
#pragma unroll
    for (int o = 0; o < 8; o++) h[o] = fmaf(wr[o], x, h[o]);
  }
#pragma unroll
  for (int o = 0; o < 8; o++) lh[(oseg * 8 + o) * 64 + wi] = fmaxf(h[o], 0.f);
  __syncthreads();  // #2: lh + lxsc complete, all lx reads (l1) done

  // ---- scale path layer 2: 64 -> 8
  float a[8];
  const float* bp2 = b2s + oseg * 8;
#pragma unroll
  for (int o = 0; o < 8; o++) a[o] = bp2[o];
#pragma unroll
  for (int c = 0; c < 64; c++) {
    float x = lh[c * 64 + wi];
    const float* wr = wm + 4608 + c * 64 + oseg * 8;
#pragma unroll
    for (int o = 0; o < 8; o++) a[o] = fmaf(wr[o], x, a[o]);
  }
#pragma unroll
  for (int o = 0; o < 8; o++) lx[(oseg * 8 + o) * 64 + wi] = a[o];
  __syncthreads();  // #3: a staged in lx, all lh reads (l2) done

  // ns-max + store xs (2 per thread); score-path l1 in same phase
#pragma unroll
  for (int m = 0; m < 2; m++) {
    int idx = m * 512 + t;
    int oc = idx >> 4, ppx = idx & 15;
    float v = lx[oc * 64 + ppx];
    v = fmaxf(v, lx[oc * 64 + 16 + ppx]);
    v = fmaxf(v, lx[oc * 64 + 32 + ppx]);
    v = fmaxf(v, lx[oc * 64 + 48 + ppx]);
    xs[(size_t)(q * 64 + oc) * HW + pxg * 16 + ppx] = v;
  }
  const float* bc1 = b1c + oseg * 8;
#pragma unroll
  for (int o = 0; o < 8; o++) h[o] = bc1[o];
#pragma unroll
  for (int c = 0; c < 12; c++) {
    float x = lxsc[c * 64 + wi];
    const float* wr = wm + 8704 + c * 64 + oseg * 8;
#pragma unroll
    for (int o = 0; o < 8; o++) h[o] = fmaf(wr[o], x, h[o]);
  }
#pragma unroll
  for (int o = 0; o < 8; o++) lh[(oseg * 8 + o) * 64 + wi] = fmaxf(h[o], 0.f);
  __syncthreads();  // #4: score-h in lh, all xs-max lx reads done

  // ---- score path layer 2: 64 -> 8
  const float* bc2 = b2c + oseg * 8;
#pragma unroll
  for (int o = 0; o < 8; o++) a[o] = bc2[o];
#pragma unroll
  for (int c = 0; c < 64; c++) {
    float x = lh[c * 64 + wi];
    const float* wr = wm + 9472 + c * 64 + oseg * 8;
#pragma unroll
    for (int o = 0; o < 8; o++) a[o] = fmaf(wr[o], x, a[o]);
  }
#pragma unroll
  for (int o = 0; o < 8; o++) lx[(oseg * 8 + o) * 64 + wi] = a[o];
  __syncthreads();  // #5

  // ns-max + store xc
#pragma unroll
  for (int m = 0; m < 2; m++) {
    int idx = m * 512 + t;
    int oc = idx >> 4, ppx = idx & 15;
    float v = lx[oc * 64 + ppx];
    v = fmaxf(v, lx[oc * 64 + 16 + ppx]);
    v = fmaxf(v, lx[oc * 64 + 32 + ppx]);
    v = fmaxf(v, lx[oc * 64 + 48 + ppx]);
    xc[(size_t)(q * 64 + oc) * HW + pxg * 16 + ppx] = v;
  }
}

// ---- merged big 3x3 conv v3: 2 rows x 16 oc per thread (og=4).
// grid 384 = hi(12: og*3+head)*32 + q*8 + rt.  Tile: 8 out rows x 64 cols.
// LDS 16ic x 10 rows x 72 stride (data at col 4..67, pads col 3 & 68) = 46 KB.
template <bool RELU>
__global__ __launch_bounds__(256) void k_conv3h(
    const float* __restrict__ in0, const float* __restrict__ in1,
    const float* __restrict__ in2, const float* __restrict__ w0,
    const float* __restrict__ w1, const float* __restrict__ w2,
    const float* __restrict__ bb0, const float* __restrict__ bb1,
    const float* __restrict__ bb2, float* __restrict__ o0,
    float* __restrict__ o1, float* __restrict__ o2) {
  __shared__ float tile[16 * 10 * 72];  // 46.1 KB -> 3 blocks/CU
  int b = blockIdx.x;
  int hi = b >> 5;  // og*3 + head, og in 0..3
  int og = hi / 3;
  int head = hi - og * 3;
  int q = (b >> 3) & 3;
  int rt = b & 7;
  const float* in = head == 0 ? in0 : head == 1 ? in1 : in2;
  const float* wT = head == 0 ? w0 : head == 1 ? w1 : w2;
  const float* bb = head == 0 ? bb0 : head == 1 ? bb1 : bb2;
  float* outp = head == 0 ? o0 : head == 1 ? o1 : o2;

  int t = threadIdx.x;
  int w = t & 63;
  int wr = t >> 6;       // 0..3 (wave-uniform): thread rows 2wr, 2wr+1
  int lane4 = t & 15;    // staging: float4 col
  int rgrp = t >> 4;     // staging: 16 rows/pass
  float acc[2][16];
#pragma unroll
  for (int pr = 0; pr < 2; pr++)
#pragma unroll
    for (int o = 0; o < 16; o++) acc[pr][o] = 0.f;
  const float* inq = in + (size_t)q * 64 * HW;

  for (int icc = 0; icc < 4; icc++) {
    __syncthreads();
    // edge pads (rows 0..159): col 3 (img -1) and col 68 (img 64)
    if (t < 160) { tile[t * 72 + 3] = 0.f; tile[t * 72 + 68] = 0.f; }
    // stage 16 ic x 10 rows x 64 cols as float4
#pragma unroll
    for (int p = 0; p < 10; p++) {
      int idx = p * 16 + rgrp;  // 0..159
      int ch = idx / 10;
      int r = idx - ch * 10;
      int grow = rt * 8 + r - 1;
      float4 val = make_float4(0.f, 0.f, 0.f, 0.f);
      if (grow >= 0 && grow < 64)
        val = *(const float4*)(inq + (size_t)(icc * 16 + ch) * HW + grow * 64 +
                               lane4 * 4);
      *(float4*)(tile + idx * 72 + 4 + lane4 * 4) = val;
    }
    __syncthreads();
#pragma unroll 2
    for (int ic = 0; ic < 16; ic++) {
      // x window: 4 tile rows x 3 cols
      float xv[4][3];
      const float* tb = tile + (ic * 10 + wr * 2) * 72 + w + 3;
#pragma unroll
      for (int rr = 0; rr < 4; rr++)
#pragma unroll
        for (int dc = 0; dc < 3; dc++) xv[rr][dc] = tb[rr * 72 + dc];
      const float* wb = wT + (size_t)(icc * 16 + ic) * 9 * 64 + og * 16;
#pragma unroll
      for (int dr = 0; dr < 3; dr++)
#pragma unroll
        for (int dc = 0; dc < 3; dc++) {
          const float* wv = wb + (dr * 3 + dc) * 64;
#pragma unroll
          for (int o = 0; o < 16; o++) {
            float wj = wv[o];
            acc[0][o] = fmaf(wj, xv[0 + dr][dc], acc[0][o]);
            acc[1][o] = fmaf(wj, xv[1 + dr][dc], acc[1][o]);
          }
        }
    }
  }
#pragma unroll
  for (int pr = 0; pr < 2; pr++) {
    int orow = rt * 8 + wr * 2 + pr;
#pragma unroll
    for (int o = 0; o < 16; o++) {
      float rz = acc[pr][o] + bb[og * 16 + o];
      if (RELU) rz = fmaxf(rz, 0.f);
      outp[((size_t)q * 64 + og * 16 + o) * HW + orow * 64 + w] = rz;
    }
  }
}

// ---- merged small 3x3 conv (heads: OC=1,2,1), 1-row blocks ----
__global__ __launch_bounds__(256) void k_convSh(
    const float* __restrict__ in0, const float* __restrict__ in1,
    const float* __restrict__ in2, const float* __restrict__ wt0,
    const float* __restrict__ wt1, const float* __restrict__ wt2,
    const float* __restrict__ bb0, const float* __restrict__ bb1,
    const float* __restrict__ bb2, float* __restrict__ o0,
    float* __restrict__ o1, float* __restrict__ o2) {
  __shared__ float tile[64 * 3 * 66];  // 50.7 KB
  __shared__ float red[4 * 2 * 64];
  int b = blockIdx.x;  // 768 = head*256 + q*64 + row
  int head = b >> 8;
  int q = (b >> 6) & 3;
  int row = b & 63;
  const float* in = head == 0 ? in0 : head == 1 ? in1 : in2;
  const float* wt = head == 0 ? wt0 : head == 1 ? wt1 : wt2;
  const float* bb = head == 0 ? bb0 : head == 1 ? bb1 : bb2;
  float* outp = head == 0 ? o0 : head == 1 ? o1 : o2;
  int noc = (head == 1) ? 2 : 1;

  int t = threadIdx.x;
  int w = t & 63;
  int sub = t >> 6;
  if (t < 192) { tile[t * 66] = 0.f; tile[t * 66 + 65] = 0.f; }
  __syncthreads();
  const float* inq = in + (size_t)q * 64 * HW;
#pragma unroll
  for (int i = 0; i < 48; i++) {
    int idx = i * 4 + sub;
    int ic = idx / 3;
    int r = idx - ic * 3;
    int grow = row + r - 1;
    float val = 0.f;
    if (grow >= 0 && grow < 64) val = inq[(size_t)ic * HW + grow * 64 + w];
    tile[idx * 66 + 1 + w] = val;
  }
  __syncthreads();
  float acc0 = 0.f, acc1 = 0.f;
#pragma unroll 4
  for (int i = 0; i < 16; i++) {
    int ic = sub * 16 + i;
    float x[9];
#pragma unroll
    for (int dr = 0; dr < 3; dr++)
#pragma unroll
      for (int dc = 0; dc < 3; dc++)
        x[dr * 3 + dc] = tile[(ic * 3 + dr) * 66 + w + dc];
    const float* wb = wt + (size_t)ic * 9;
#pragma unroll
    for (int j = 0; j < 9; j++) acc0 += wb[j] * x[j];
    if (noc == 2) {
      const float* wb1 = wt + 576 + (size_t)ic * 9;
#pragma unroll
      for (int j = 0; j < 9; j++) acc1 += wb1[j] * x[j];
    }
  }
  red[(sub * 2 + 0) * 64 + w] = acc0;
  if (noc == 2) red[(sub * 2 + 1) * 64 + w] = acc1;
  __syncthreads();
  if (t < 128) {
    int o = t >> 6;
    if (o < noc) {
      float s = red[(0 * 2 + o) * 64 + w] + red[(1 * 2 + o) * 64 + w] +
                red[(2 * 2 + o) * 64 + w] + red[(3 * 2 + o) * 64 + w] + bb[o];
      outp[((size_t)q * noc + o) * HW + row * 64 + w] = s;
    }
  }
}

// ---------------- final: argmax + pos/scl ----------------
__global__ __launch_bounds__(256) void k_final(const float* __restrict__ scores,
                                               const float* __restrict__ scales,
                                               const float* __restrict__ offsets,
                                               float* __restrict__ pos,
                                               float* __restrict__ sclo) {
  int q = blockIdx.x, t = threadIdx.x;
  float best = -3.4e38f;
  int bi = 1 << 30;
  for (int i = t; i < HW; i += 256) {
    float v = scores[q * HW + i];
    if (v > best) { best = v; bi = i; }
  }
  __shared__ float bv[256];
  __shared__ int bix[256];
  bv[t] = best;
  bix[t] = bi;
  __syncthreads();
  for (int s = 128; s > 0; s >>= 1) {
    if (t < s) {
      if (bv[t + s] > bv[t] || (bv[t + s] == bv[t] && bix[t + s] < bix[t])) {
        bv[t] = bv[t + s];
        bix[t] = bix[t + s];
      }
    }
    __syncthreads();
  }
  if (t == 0) {
    int sid = bix[0];
    int sy = sid >> 6, sx = sid & 63;
    float o0 = offsets[(q * 2 + 0) * HW + sid];
    float o1 = offsets[(q * 2 + 1) * HW + sid];
    pos[q * 2 + 0] = ((float)sx + o0 + 0.5f) * 8.f - 0.5f;
    pos[q * 2 + 1] = ((float)sy + o1 + 0.5f) * 8.f - 0.5f;
    sclo[q] = exp2f(scales[q * HW + sid]);
  }
}

extern "C" void kernel_launch(void* const* d_in, const int* in_sizes, int n_in,
                              void* d_out, int out_size, void* d_ws, size_t ws_size,
                              hipStream_t stream) {
  const float* corr = (const float*)d_in[0];
  const float* w1s = (const float*)d_in[1];
  const float* b1s = (const float*)d_in[2];
  const float* w2s = (const float*)d_in[3];
  const float* b2s = (const float*)d_in[4];
  const float* w1c = (const float*)d_in[5];
  const float* b1c = (const float*)d_in[6];
  const float* w2c = (const float*)d_in[7];
  const float* b2c = (const float*)d_in[8];

  float* out = (float*)d_out;
  float* pos = out;                   // (4,2)
  float* sclo = out + 8;              // (4,)
  float* scores = out + 12;           // (4,1,64,64)
  float* scales = out + 12 + 16384;   // (4,1,64,64)
  float* offsets = out + 12 + 32768;  // (4,2,64,64)

  char* ws = (char*)d_ws;
  float* st_scl = (float*)(ws + 0);       // 36 KB
  float* st_shf = (float*)(ws + 36864);   // 36 KB
  int* topidx = (int*)(ws + 73728);       // 1 MB
  float* rs = (float*)(ws + 1122304);     // 8.39 MB (dead after k_topk)
  float* wT = (float*)(ws + 19996672);    // 884 KB (big-conv transposed w)
  float* wmT = (float*)(ws + 20881408);   // 54 KB (MLP transposed w)
  float* xs = (float*)(ws + 20971520);    // 4.19 MB
  float* xc = (float*)(ws + 25165824);    // 4.19 MB  (total 29.4 MB)
  // t1/t2 reuse dead regions (stream-ordered):
  float* t1s = rs;                           // rs dead after k_topk
  float* t1o = (float*)((char*)rs + 4194304);
  float* t1c = (float*)((char*)rs + 8388608);
  float* t2c = (float*)((char*)rs + 12582912);
  float* t2s = xs;                           // xs dead after conv layer 1
  float* t2o = xc;                           // xc dead after conv layer 1

  k_statsrs<<<661, 256, 0, stream>>>(
      corr, st_scl, st_shf, rs, (const float*)d_in[9], (const float*)d_in[11],
      (const float*)d_in[15], (const float*)d_in[17], (const float*)d_in[21],
      (const float*)d_in[23], wT, w1s, w2s, w1c, w2c, wmT);
  k_topk<<<256, 256, 0, stream>>>(rs, topidx);
  k_mlp3<<<1024, 512, 0, stream>>>(corr, st_scl, st_shf, topidx, wmT, b1s, b2s,
                                   b1c, b2c, xs, xc);
  // conv layer 1 (all heads): xs->t1s, xc->t1o, xc->t1c
  k_conv3h<true><<<384, 256, 0, stream>>>(
      xs, xc, xc, wT, wT + 2 * 36864, wT + 4 * 36864,
      (const float*)d_in[10], (const float*)d_in[16], (const float*)d_in[22],
      t1s, t1o, t1c);
  // conv layer 2 (all heads): t1*->t2*
  k_conv3h<true><<<384, 256, 0, stream>>>(
      t1s, t1o, t1c, wT + 1 * 36864, wT + 3 * 36864, wT + 5 * 36864,
      (const float*)d_in[12], (const float*)d_in[18], (const float*)d_in[24],
      t2s, t2o, t2c);
  // conv layer 3 (all heads): t2* -> scales/offsets/scores
  k_convSh<<<768, 256, 0, stream>>>(
      t2s, t2o, t2c, (const float*)d_in[13], (const float*)d_in[19],
      (const float*)d_in[25], (const float*)d_in[14], (const float*)d_in[20],
      (const float*)d_in[26], scales, offsets, scores);

  k_final<<<4, 256, 0, stream>>>(scores, scales, offsets, pos, sclo);
}